// Round 9
// baseline (338.886 us; speedup 1.0000x reference)
//
#include <hip/hip_runtime.h>
#include <math.h>

#define PI_F   3.14159265358979f
#define QF     0.88249690258459546f   /* exp(-1/8) */
#define INV255 (1.0f/255.0f)

__device__ __forceinline__ float softplus_f(float x){
    return fmaxf(x, 0.0f) + __logf(1.0f + __expf(-fabsf(x)));
}
__device__ __forceinline__ float tanh_fast(float x){
    const float e = __expf(2.0f*x);
    return fmaf(-2.0f, __builtin_amdgcn_rcpf(e + 1.0f), 1.0f);
}

/* ---- lane exchanges (all HW-verified equivalent R1==R2; row_ror:8 verified R11) ---- */
template<int CTRL>
__device__ __forceinline__ float dppmov(float x){
    return __int_as_float(__builtin_amdgcn_mov_dpp(__float_as_int(x), CTRL, 0xF, 0xF, false));
}
__device__ __forceinline__ float lxor1 (float x){ return dppmov<0xB1>(x);  }  /* quad_perm(1,0,3,2) */
__device__ __forceinline__ float lxor2 (float x){ return dppmov<0x4E>(x);  }  /* quad_perm(2,3,0,1) */
__device__ __forceinline__ float lxor8 (float x){ return dppmov<0x128>(x); }  /* row_ror:8 == i^8   */
__device__ __forceinline__ float lxor4 (float x){ return __int_as_float(__builtin_amdgcn_ds_swizzle(__float_as_int(x), 0x101F)); }
__device__ __forceinline__ float lxor16(float x){ return __int_as_float(__builtin_amdgcn_ds_swizzle(__float_as_int(x), 0x401F)); }
__device__ __forceinline__ float lxor32(float x){ return __shfl_xor(x, 32, 64); }

template<int CTRL>
__device__ __forceinline__ float dppadd(float v){
    return v + __int_as_float(__builtin_amdgcn_update_dpp(0, __float_as_int(v), CTRL, 0xF, 0xF, true));
}
/* full 64-lane sum, result valid in lane 63 (verified R11) */
__device__ __forceinline__ float wave_sum63(float v){
    v = dppadd<0x111>(v);   /* row_shr:1  */
    v = dppadd<0x112>(v);   /* row_shr:2  */
    v = dppadd<0x114>(v);   /* row_shr:4  */
    v = dppadd<0x118>(v);   /* row_shr:8  */
    v = dppadd<0x142>(v);   /* row_bcast:15 */
    v = dppadd<0x143>(v);   /* row_bcast:31 */
    return v;
}

/* Weighted-Hadamard butterfly, bits 0..5 on lanes, 6..7 on regs. Stages commute. */
template<int NA>
__device__ __forceinline__ void bflyN(float (&x)[NA][4]){
    const float qv = QF;
    #pragma unroll
    for (int a = 0; a < NA; a++){
        #pragma unroll
        for (int r = 0; r < 4; r++) x[a][r] = fmaf(lxor1 (x[a][r]), qv, x[a][r]);
    }
    #pragma unroll
    for (int a = 0; a < NA; a++){
        #pragma unroll
        for (int r = 0; r < 4; r++) x[a][r] = fmaf(lxor2 (x[a][r]), qv, x[a][r]);
    }
    #pragma unroll
    for (int a = 0; a < NA; a++){
        #pragma unroll
        for (int r = 0; r < 4; r++) x[a][r] = fmaf(lxor8 (x[a][r]), qv, x[a][r]);
    }
    #pragma unroll
    for (int a = 0; a < NA; a++){
        #pragma unroll
        for (int r = 0; r < 4; r++) x[a][r] = fmaf(lxor4 (x[a][r]), qv, x[a][r]);
    }
    #pragma unroll
    for (int a = 0; a < NA; a++){
        #pragma unroll
        for (int r = 0; r < 4; r++) x[a][r] = fmaf(lxor16(x[a][r]), qv, x[a][r]);
    }
    #pragma unroll
    for (int a = 0; a < NA; a++){
        #pragma unroll
        for (int r = 0; r < 4; r++) x[a][r] = fmaf(lxor32(x[a][r]), qv, x[a][r]);
    }
    #pragma unroll
    for (int a = 0; a < NA; a++){
        float t0 = x[a][0], t2 = x[a][2];
        x[a][0] = fmaf(QF, x[a][1], x[a][0]);
        x[a][1] = fmaf(QF, t0,      x[a][1]);
        x[a][2] = fmaf(QF, x[a][3], x[a][2]);
        x[a][3] = fmaf(QF, t2,      x[a][3]);
        t0 = x[a][0]; float t1 = x[a][1];
        x[a][0] = fmaf(QF, x[a][2], x[a][0]);
        x[a][1] = fmaf(QF, x[a][3], x[a][1]);
        x[a][2] = fmaf(QF, t0,      x[a][2]);
        x[a][3] = fmaf(QF, t1,      x[a][3]);
    }
}

/* ---- prep: blocks 0..31 transpose Ws -> WsT[512][256];
       block 32: iteration-0 peel constants X,P0,phi0 [32][256] (batch-independent) ---- */
__global__ __launch_bounds__(256) void prep_kernel(
        const float* __restrict__ Ws,    const float* __restrict__ psiA0,
        const float* __restrict__ psiP0, const float* __restrict__ p_alpha,
        const float* __restrict__ p_msq, const float* __restrict__ p_pw,
        const float* __restrict__ p_iw,  const float* __restrict__ p_evo,
        float* __restrict__ WsT,  float* __restrict__ Xc,  float* __restrict__ P0c,
        float* __restrict__ F0c)
{
    if (blockIdx.x < 32){
        __shared__ float tile[64][65];
        const int rt = blockIdx.x & 3, ct = blockIdx.x >> 2;
        const int r0 = rt*64, c0t = ct*64;
        const int tx = threadIdx.x & 63, ty = threadIdx.x >> 6;
        #pragma unroll
        for (int k = 0; k < 16; k++){
            const int row = ty*16 + k;
            tile[row][tx] = Ws[(r0+row)*512 + c0t + tx];
        }
        __syncthreads();
        #pragma unroll
        for (int k = 0; k < 16; k++){
            const int row = ty*16 + k;
            WsT[(c0t+row)*256 + r0 + tx] = tile[tx][row];
        }
        return;
    }
    /* block 32: batch-independent iteration-0 dynamics */
    const int tid = threadIdx.x;
    const int w = tid >> 6, l = tid & 63;
    const float alpha = p_alpha[0], msq = p_msq[0], pw = p_pw[0], iw = p_iw[0];
    const float dt   = 1.0f / (1.0f + __expf(-p_evo[0]));
    const float dta  = dt * alpha * INV255;
    const float dtpw = dt * pw * INV255;
    const float c0   = 1.0f - dt * (msq + iw);
    const float m0 = (l == 0) ? 0.0f : 1.0f;
    int nn[4]; float krow[4];
    float c18;
    { const float t1 = 1.0f + QF, t2 = t1*t1, t4 = t2*t2; c18 = t4*t4; }
    #pragma unroll
    for (int r = 0; r < 4; r++){
        nn[r] = l + 64*r;
        krow[r] = c18 - __expf(-0.125f * (float)__popc(nn[r]));
    }
    #pragma unroll
    for (int dd = 0; dd < 8; dd++){
        const int d = w*8 + dd;
        float A0[4], ph0[4], sp[4], cp[4];
        float x[5][4];
        #pragma unroll
        for (int r = 0; r < 4; r++){
            const int n = nn[r];
            A0[r]  = (n > 0) ? softplus_f(psiA0[(n-1)*32 + d]) : 0.0f;
            ph0[r] = (n > 0) ? psiP0[(n-1)*32 + d] : 0.0f;
            sp[r] = __sinf(ph0[r]); cp[r] = __cosf(ph0[r]);
            const float mk = (r == 0) ? m0 : 1.0f;
            const float xa = A0[r] * mk;
            x[0][r] = xa;
            x[1][r] = sp[r] * mk;
            x[2][r] = cp[r] * mk;
            x[3][r] = xa * cp[r];
            x[4][r] = xa * sp[r];
        }
        bflyN<5>(x);
        #pragma unroll
        for (int r = 0; r < 4; r++){
            const float Ao   = A0[r];
            const float lapp = fmaf(-krow[r], Ao, x[0][r]);
            const float Vp   = fmaf(cp[r], x[3][r], sp[r]*x[4][r]);
            const float Pp   = fmaf(-sp[r], x[2][r], cp[r]*x[1][r]);
            float X = c0 * Ao;
            X = fmaf(dta,  lapp, X);
            X = fmaf(dtpw, Vp,   X);
            const int idx = d*256 + nn[r];
            Xc[idx]  = X;
            P0c[idx] = dta * Ao * Pp;
            F0c[idx] = ph0[r];
        }
    }
}

/* ---------------- fused kernel: one block = one batch element, 1024 threads (16 waves).
   R7 proved the dd=2 body fits the 8-waves/SIMD reg bucket (VGPR 60 <= 64, zero
   spill) — but its 85KB LDS forced 1 block/CU, exposing every block-wide barrier
   (VALUBusy 51%, 283us vs R3's 213 with 2-block overlap).
   THIS ROUND: same body, LDS 85 -> 77KB (<=80KB -> 2 blocks/CU = 32 waves/CU):
   the 16KB 16-partial norm buffer becomes an 8KB TWO-STAGE reduction
   (waves 0-7 write, barrier, waves 8-15 +=, barrier, all read 8 partials).
   One extra barrier per norm phase, but with a co-resident block every barrier
   overlaps the other block's compute.
   drive identity: Dsp*cos(phi) - Dcp*sin(phi) == CAp * sin(Pin - phi).
   peel-0 + 3 full iters + peel-4 ------- */
template<bool USET>
__global__ __launch_bounds__(1024) void fused_kernel(
        const float* __restrict__ ns,     /* [B][512] */
        const float* __restrict__ Ws,     /* [256][512] */
        const float* __restrict__ WsT,    /* [512][256] or null */
        const float* __restrict__ bs,     /* [256] */
        const float* __restrict__ WA,     /* [32][32] */
        const float* __restrict__ bA,     /* [32] */
        const float* __restrict__ WP,     /* [32][32] */
        const float* __restrict__ bP,     /* [32] */
        const float* __restrict__ psiA0,  /* [255*32] */
        const float* __restrict__ psiP0,  /* [255*32] */
        const float* __restrict__ Xc,     /* [32][256] or null */
        const float* __restrict__ P0c,    /* [32][256] or null */
        const float* __restrict__ F0c,    /* [32][256] or null */
        const float* __restrict__ Wcomp,  /* [32*255] */
        const float* __restrict__ bcomp,  /* [32] */
        const float* __restrict__ Wread,  /* [64*1024] */
        const float* __restrict__ bread,  /* [64] */
        const float* __restrict__ p_alpha, const float* __restrict__ p_msq,
        const float* __restrict__ p_pw,    const float* __restrict__ p_iw,
        const float* __restrict__ p_evo,   const float* __restrict__ p_pcpl,
        float* __restrict__ out, int Bb)
{
    /* 77 KB total -> 2 blocks/CU (32 waves/CU) */
    __shared__ __align__(16) float2 CP[8][1024];    /* 64 KB: {CAp, Pin} per (k=dd*4+r, tid) */
    __shared__ __align__(16) float  red[2048];      /* 8 KB: 2-stage norm partials / GEMV partials; aliased ac/rop at readout */
    __shared__ __align__(16) float  hA[256];
    __shared__ __align__(16) float  hP[256];
    __shared__ __align__(16) float  nsb[512];
    __shared__ __align__(16) float  fe[256];

    float* ac  = red;          /* [1024] readout stage 1 (red dead by then) */
    float* rop = red + 1024;   /* [1024] readout stage 2 */

    const int b   = blockIdx.x;
    const int tid = threadIdx.x;
    const int w   = tid >> 6, l = tid & 63;

    const float alpha = p_alpha[0], msq = p_msq[0], pw = p_pw[0], iw = p_iw[0];
    const float pcpl  = p_pcpl[0];
    const float dt    = 1.0f / (1.0f + __expf(-p_evo[0]));
    const float dta  = dt * alpha * INV255;
    const float dtpw = dt * pw * INV255;
    const float c0   = 1.0f - dt * (msq + iw);
    const float dtiw = dt * iw;

    /* ---- front-end: fe[f] = ns[b]·Ws_row(f) + bs[f]; 1024 threads, 4 partials per f ---- */
    if (tid < 512) nsb[tid] = ns[b*512 + tid];
    __syncthreads();
    {
        const int k = tid >> 2, part = tid & 3;
        float f = (part == 0) ? bs[k] : 0.0f;
        if (USET){
            const float4* nb4 = (const float4*)nsb + part*32;
            const float*  colb = WsT + (part*128)*256 + k;
            #pragma unroll 8
            for (int j4 = 0; j4 < 32; j4++){
                const float4 nv = nb4[j4];
                const float* col = colb + j4*1024;
                f = fmaf(col[0],   nv.x, f);
                f = fmaf(col[256], nv.y, f);
                f = fmaf(col[512], nv.z, f);
                f = fmaf(col[768], nv.w, f);
            }
        } else {
            const float4* wr  = (const float4*)(Ws + k*512) + part*32;
            const float4* nb4 = (const float4*)nsb + part*32;
            #pragma unroll 8
            for (int i = 0; i < 32; i++){
                const float4 wv = wr[i], nv = nb4[i];
                f = fmaf(wv.x, nv.x, f); f = fmaf(wv.y, nv.y, f);
                f = fmaf(wv.z, nv.z, f); f = fmaf(wv.w, nv.w, f);
            }
        }
        red[part*256 + k] = f;
    }
    __syncthreads();
    if (tid < 256) fe[tid] = red[tid] + red[256 + tid] + red[512 + tid] + red[768 + tid];
    __syncthreads();
    {   /* fold through W_A / W_phi (linearity of the member-mean); threads 0-255 -> hA, 256-511 -> hP */
        if (tid < 512){
            const int t2 = tid & 255;
            const int s = t2 >> 5, d2 = t2 & 31;
            const float* Wm = (tid < 256) ? WA : WP;
            float acc = 0.0f;
            #pragma unroll 8
            for (int dp = 0; dp < 32; dp++)
                acc = fmaf(Wm[d2*32 + dp], fe[s*32 + dp], acc);
            if (tid < 256) hA[t2] = acc; else hP[t2] = acc;
        }
    }
    __syncthreads();

    /* per-thread clique constants: n = l + 64r */
    int   nn[4];
    float krow[4];
    const float m0 = (l == 0) ? 0.0f : 1.0f;
    float c18;
    { const float t1 = 1.0f + QF, t2 = t1*t1, t4 = t2*t2; c18 = t4*t4; }
    #pragma unroll
    for (int r = 0; r < 4; r++){
        nn[r] = l + 64*r;
        krow[r] = c18 - __expf(-0.125f * (float)__popc(nn[r]));
    }

    /* state + drive terms + ITERATION-0 PEEL (batch-dep part only); d = w*2 + dd
       drive {CAp, Pin} -> LDS own-slot; only {A, phi} persist in registers */
    float A[2][4], phi[2][4];
    float nrm0[4] = {0.f, 0.f, 0.f, 0.f};

    #pragma unroll
    for (int dd = 0; dd < 2; dd++){
        const int d = w*2 + dd;
        const float bAd = bA[d], bPd = bP[d];
        float gA_[8], gP_[8];
        #pragma unroll
        for (int s = 0; s < 8; s++){ gA_[s] = hA[s*32 + d]; gP_[s] = hP[s*32 + d]; }
        #pragma unroll
        for (int r = 0; r < 4; r++){
            const int pop = __popc(nn[r]);
            const float rdep = 1.0f / (float)(pop ? pop : 1);
            float sA = 0.0f, sP = 0.0f;
            #pragma unroll
            for (int s = 0; s < 8; s++){
                if ((nn[r] >> s) & 1){ sA += gA_[s]; sP += gP_[s]; }
            }
            const float uA  = fmaf(sA, rdep, bAd);
            const float uP  = fmaf(sP, rdep, bPd);
            const float Ain = softplus_f(uA);
            const float pin = PI_F * tanh_fast(uP);
            const float ca = dtiw * Ain;
            CP[dd*4 + r][tid] = make_float2(ca, pin);   /* own slot, no sync needed */
            if (USET){
                /* iter-0 peel: A1 = softplus(X + ca); phi1 = F0 + P0/A1 + ca*sin(pin-F0) */
                const int idx = d*256 + nn[r];
                const float An = softplus_f(Xc[idx] + ca);
                const float rr = __builtin_amdgcn_rcpf(An + 1e-8f);
                const float F0 = F0c[idx];
                float pb = fmaf(ca, __sinf(pin - F0), F0);
                phi[dd][r] = fmaf(P0c[idx], rr, pb);
                A[dd][r]   = An;
                nrm0[r]    = fmaf(An, An, nrm0[r]);
            } else {
                const int nm1 = (nn[r] > 0) ? (nn[r] - 1) : 0;
                A[dd][r]   = softplus_f(psiA0[nm1*32 + d]);
                phi[dd][r] = psiP0[nm1*32 + d];
            }
        }
    }

    if (USET){
        /* norm-clip for peeled iteration 0; 2-stage 8-slot reduction */
        if (w < 8){
            #pragma unroll
            for (int r = 0; r < 4; r++) red[w*256 + nn[r]] = nrm0[r];
        }
        __syncthreads();
        if (w >= 8){
            #pragma unroll
            for (int r = 0; r < 4; r++) red[(w-8)*256 + nn[r]] += nrm0[r];
        }
        __syncthreads();
        float scl[4];
        #pragma unroll
        for (int r = 0; r < 4; r++){
            const int n = nn[r];
            const float t = red[n]        + red[256 + n]  + red[512 + n]  + red[768 + n]
                          + red[1024 + n] + red[1280 + n] + red[1536 + n] + red[1792 + n];
            scl[r] = (t > 1.0f) ? rsqrtf(t) : 1.0f;
        }
        __syncthreads();   /* protect red against next writer */
        #pragma unroll
        for (int dd = 0; dd < 2; dd++)
            #pragma unroll
            for (int r = 0; r < 4; r++) A[dd][r] *= scl[r];
    }

    /* ---- full iterations (3 when peeled, 4 otherwise) ---- */
    const int NFULL = USET ? 3 : 4;
    for (int it = 0; it < NFULL; it++){
        float nrm[4] = {0.f, 0.f, 0.f, 0.f};
        #pragma unroll
        for (int dd = 0; dd < 2; dd++){
            float sp[4], cp[4];
            float x[5][4];
            {
                sp[0] = __sinf(phi[dd][0]); cp[0] = __cosf(phi[dd][0]);
                const float xa = A[dd][0] * m0;
                x[0][0] = xa;
                x[1][0] = sp[0] * m0;
                x[2][0] = cp[0] * m0;
                x[3][0] = xa * cp[0];
                x[4][0] = xa * sp[0];
            }
            #pragma unroll
            for (int r = 1; r < 4; r++){
                sp[r] = __sinf(phi[dd][r]); cp[r] = __cosf(phi[dd][r]);
                const float xa = A[dd][r];
                x[0][r] = xa;
                x[1][r] = sp[r];
                x[2][r] = cp[r];
                x[3][r] = xa * cp[r];
                x[4][r] = xa * sp[r];
            }
            bflyN<5>(x);
            #pragma unroll
            for (int r = 0; r < 4; r++){
                const float2 cpn = CP[dd*4 + r][tid];   /* {CAp, Pin} */
                const float Ao   = A[dd][r];
                const float lapp = fmaf(-krow[r], Ao, x[0][r]);
                const float Vp   = fmaf(cp[r], x[3][r], sp[r]*x[4][r]);
                float Aarg = fmaf(c0, Ao, cpn.x);
                Aarg = fmaf(dta,  lapp, Aarg);
                Aarg = fmaf(dtpw, Vp,   Aarg);
                const float An = softplus_f(Aarg);
                const float Pp = fmaf(-sp[r], x[2][r], cp[r]*x[1][r]);
                const float rr = __builtin_amdgcn_rcpf(An + 1e-8f);
                const float sdr = __sinf(cpn.y - phi[dd][r]);
                float pb = fmaf(cpn.x, sdr, phi[dd][r]);
                phi[dd][r] = fmaf(dta*Ao, Pp*rr, pb);
                A[dd][r]   = An;
                nrm[r]     = fmaf(An, An, nrm[r]);
            }
        }
        if (w < 8){
            #pragma unroll
            for (int r = 0; r < 4; r++) red[w*256 + nn[r]] = nrm[r];
        }
        __syncthreads();
        if (w >= 8){
            #pragma unroll
            for (int r = 0; r < 4; r++) red[(w-8)*256 + nn[r]] += nrm[r];
        }
        __syncthreads();
        float scl[4];
        #pragma unroll
        for (int r = 0; r < 4; r++){
            const int n = nn[r];
            const float t = red[n]        + red[256 + n]  + red[512 + n]  + red[768 + n]
                          + red[1024 + n] + red[1280 + n] + red[1536 + n] + red[1792 + n];
            scl[r] = (t > 1.0f) ? rsqrtf(t) : 1.0f;
        }
        __syncthreads();   /* protect red against next iteration's writer */
        #pragma unroll
        for (int dd = 0; dd < 2; dd++)
            #pragma unroll
            for (int r = 0; r < 4; r++) A[dd][r] *= scl[r];
    }

    /* ---- final iteration (peeled): phi-update dead -> 3-array butterfly, A-only epilogue ---- */
    {
        float nrm[4] = {0.f, 0.f, 0.f, 0.f};
        #pragma unroll
        for (int dd = 0; dd < 2; dd++){
            float sp[4], cp[4];
            float y[3][4];
            {
                sp[0] = __sinf(phi[dd][0]); cp[0] = __cosf(phi[dd][0]);
                const float xa = A[dd][0] * m0;
                y[0][0] = xa;
                y[1][0] = xa * cp[0];
                y[2][0] = xa * sp[0];
            }
            #pragma unroll
            for (int r = 1; r < 4; r++){
                sp[r] = __sinf(phi[dd][r]); cp[r] = __cosf(phi[dd][r]);
                const float xa = A[dd][r];
                y[0][r] = xa;
                y[1][r] = xa * cp[r];
                y[2][r] = xa * sp[r];
            }
            bflyN<3>(y);
            #pragma unroll
            for (int r = 0; r < 4; r++){
                const float Ao   = A[dd][r];
                const float lapp = fmaf(-krow[r], Ao, y[0][r]);
                const float Vp   = fmaf(cp[r], y[1][r], sp[r]*y[2][r]);
                float Aarg = fmaf(c0, Ao, CP[dd*4 + r][tid].x);
                Aarg = fmaf(dta,  lapp, Aarg);
                Aarg = fmaf(dtpw, Vp,   Aarg);
                const float An = softplus_f(Aarg);
                A[dd][r]   = An;
                nrm[r]     = fmaf(An, An, nrm[r]);
            }
        }
        if (w < 8){
            #pragma unroll
            for (int r = 0; r < 4; r++) red[w*256 + nn[r]] = nrm[r];
        }
        __syncthreads();
        if (w >= 8){
            #pragma unroll
            for (int r = 0; r < 4; r++) red[(w-8)*256 + nn[r]] += nrm[r];
        }
        __syncthreads();
        float scl[4];
        #pragma unroll
        for (int r = 0; r < 4; r++){
            const int n = nn[r];
            const float t = red[n]        + red[256 + n]  + red[512 + n]  + red[768 + n]
                          + red[1024 + n] + red[1280 + n] + red[1536 + n] + red[1792 + n];
            scl[r] = (t > 1.0f) ? rsqrtf(t) : 1.0f;
        }
        __syncthreads();   /* red is about to be reused as ac[] */
        #pragma unroll
        for (int dd = 0; dd < 2; dd++)
            #pragma unroll
            for (int r = 0; r < 4; r++) A[dd][r] *= scl[r];
    }

    /* ---- readout: Ac[d][c] = relu(sum_n Wcomp[c][n-1] A[n][d] + bcomp[c]); DPP wave-sum ---- */
    #pragma unroll
    for (int dd = 0; dd < 2; dd++) A[dd][0] *= m0;   /* kill n==0 slot */

    for (int c = 0; c < 32; c++){
        float wv[4];
        #pragma unroll
        for (int r = 0; r < 4; r++){
            const int idx = c*255 + nn[r] - 1;
            wv[r] = Wcomp[idx < 0 ? 0 : idx];
        }
        const float bc = bcomp[c];
        #pragma unroll
        for (int dd = 0; dd < 2; dd++){
            float v = wv[0] * A[dd][0];
            v = fmaf(wv[1], A[dd][1], v);
            v = fmaf(wv[2], A[dd][2], v);
            v = fmaf(wv[3], A[dd][3], v);
            v = wave_sum63(v);
            if (l == 63)
                ac[(w*2 + dd)*32 + c] = fmaxf(v + bc, 0.0f);
        }
    }
    __syncthreads();

    /* ro[k] = sum_j Wread[k][j] * ac[j] + bread[k]; k = 0..63 split over 16 partials */
    {
        const int k = tid >> 4, part = tid & 15;
        const float4* Wr4 = (const float4*)Wread + k*256;
        const float4* ac4 = (const float4*)ac;
        float s = 0.0f;
        #pragma unroll 4
        for (int jj = 0; jj < 16; jj++){
            const int j4 = part + 16*jj;
            const float4 wv = Wr4[j4];
            const float4 av = ac4[j4];
            s = fmaf(wv.x, av.x, s); s = fmaf(wv.y, av.y, s);
            s = fmaf(wv.z, av.z, s); s = fmaf(wv.w, av.w, s);
        }
        rop[tid] = s;
    }
    __syncthreads();
    if (tid < 32){
        float ra = bread[tid], rp = bread[tid + 32];
        #pragma unroll
        for (int p = 0; p < 16; p++){
            ra += rop[tid*16 + p];
            rp += rop[(tid + 32)*16 + p];
        }
        const float amp = softplus_f(ra);
        const float ph  = PI_F * tanhf(rp * pcpl);
        const float cph = __cosf(ph);
        /* PLANAR output (verified R7): chunk0 = Re(psi), chunk1 = amplitude, chunk2 = phase */
        const int o = b*32 + tid;
        out[o]         = amp * cph;   /* Re(psi) */
        out[Bb*32 + o] = amp;         /* amplitude */
        out[Bb*64 + o] = ph;          /* phase */
    }
}

extern "C" void kernel_launch(void* const* d_in, const int* in_sizes, int n_in,
                              void* d_out, int out_size, void* d_ws, size_t ws_size,
                              hipStream_t stream) {
    const float* ns      = (const float*)d_in[0];   /* [B][512] */
    const float* Ws      = (const float*)d_in[1];   /* [256][512] */
    const float* bs      = (const float*)d_in[2];   /* [256] */
    const float* WA      = (const float*)d_in[3];   /* [32][32] */
    const float* bA      = (const float*)d_in[4];   /* [32] */
    const float* WP      = (const float*)d_in[5];   /* [32][32] */
    const float* bP      = (const float*)d_in[6];   /* [32] */
    const float* psiA0   = (const float*)d_in[7];   /* [255*32] */
    const float* psiP0   = (const float*)d_in[8];   /* [255*32] */
    const float* Wcomp   = (const float*)d_in[9];   /* [32*255] */
    const float* bcomp   = (const float*)d_in[10];  /* [32] */
    const float* Wread   = (const float*)d_in[11];  /* [64*1024] */
    const float* bread   = (const float*)d_in[12];  /* [64] */
    const float* p_alpha = (const float*)d_in[13];
    const float* p_msq   = (const float*)d_in[14];
    const float* p_pw    = (const float*)d_in[15];
    const float* p_iw    = (const float*)d_in[16];
    const float* p_evo   = (const float*)d_in[17];
    const float* p_pcpl  = (const float*)d_in[18];

    const int Bb = in_sizes[0] / 512;               /* 1024 */

    const size_t need = (size_t)(512*256 + 3*32*256) * sizeof(float);
    if (ws_size >= need){
        float* WsT = (float*)d_ws;                  /* [512][256] */
        float* Xc  = WsT + 512*256;                 /* [32][256] each */
        float* P0c = Xc  + 32*256;
        float* F0c = P0c + 32*256;
        prep_kernel<<<33, 256, 0, stream>>>(Ws, psiA0, psiP0,
                                            p_alpha, p_msq, p_pw, p_iw, p_evo,
                                            WsT, Xc, P0c, F0c);
        fused_kernel<true><<<Bb, 1024, 0, stream>>>(ns, Ws, WsT, bs, WA, bA, WP, bP,
                                                    psiA0, psiP0, Xc, P0c, F0c,
                                                    Wcomp, bcomp, Wread, bread,
                                                    p_alpha, p_msq, p_pw, p_iw,
                                                    p_evo, p_pcpl, (float*)d_out, Bb);
    } else {
        fused_kernel<false><<<Bb, 1024, 0, stream>>>(ns, Ws, nullptr, bs, WA, bA, WP, bP,
                                                     psiA0, psiP0,
                                                     nullptr, nullptr, nullptr,
                                                     Wcomp, bcomp, Wread, bread,
                                                     p_alpha, p_msq, p_pw, p_iw,
                                                     p_evo, p_pcpl, (float*)d_out, Bb);
    }
}

// Round 10
// 286.092 us; speedup vs baseline: 1.1845x; 1.1845x over previous
//
#include <hip/hip_runtime.h>
#include <math.h>

#define PI_F   3.14159265358979f
#define QF     0.88249690258459546f   /* exp(-1/8) */
#define INV255 (1.0f/255.0f)

__device__ __forceinline__ float softplus_f(float x){
    return fmaxf(x, 0.0f) + __logf(1.0f + __expf(-fabsf(x)));
}
__device__ __forceinline__ float tanh_fast(float x){
    const float e = __expf(2.0f*x);
    return fmaf(-2.0f, __builtin_amdgcn_rcpf(e + 1.0f), 1.0f);
}

/* ---- lane exchanges (all HW-verified equivalent R1==R2; row_ror:8 verified R11) ---- */
template<int CTRL>
__device__ __forceinline__ float dppmov(float x){
    return __int_as_float(__builtin_amdgcn_mov_dpp(__float_as_int(x), CTRL, 0xF, 0xF, false));
}
__device__ __forceinline__ float lxor1 (float x){ return dppmov<0xB1>(x);  }  /* quad_perm(1,0,3,2) */
__device__ __forceinline__ float lxor2 (float x){ return dppmov<0x4E>(x);  }  /* quad_perm(2,3,0,1) */
__device__ __forceinline__ float lxor8 (float x){ return dppmov<0x128>(x); }  /* row_ror:8 == i^8   */
__device__ __forceinline__ float lxor4 (float x){ return __int_as_float(__builtin_amdgcn_ds_swizzle(__float_as_int(x), 0x101F)); }
__device__ __forceinline__ float lxor16(float x){ return __int_as_float(__builtin_amdgcn_ds_swizzle(__float_as_int(x), 0x401F)); }
__device__ __forceinline__ float lxor32(float x){ return __shfl_xor(x, 32, 64); }

template<int CTRL>
__device__ __forceinline__ float dppadd(float v){
    return v + __int_as_float(__builtin_amdgcn_update_dpp(0, __float_as_int(v), CTRL, 0xF, 0xF, true));
}
/* full 64-lane sum, result valid in lane 63 (verified R11) */
__device__ __forceinline__ float wave_sum63(float v){
    v = dppadd<0x111>(v);   /* row_shr:1  */
    v = dppadd<0x112>(v);   /* row_shr:2  */
    v = dppadd<0x114>(v);   /* row_shr:4  */
    v = dppadd<0x118>(v);   /* row_shr:8  */
    v = dppadd<0x142>(v);   /* row_bcast:15 */
    v = dppadd<0x143>(v);   /* row_bcast:31 */
    return v;
}

/* Weighted-Hadamard butterfly, bits 0..5 on lanes, 6..7 on regs. Stages commute. */
template<int NA>
__device__ __forceinline__ void bflyN(float (&x)[NA][4]){
    const float qv = QF;
    #pragma unroll
    for (int a = 0; a < NA; a++){
        #pragma unroll
        for (int r = 0; r < 4; r++) x[a][r] = fmaf(lxor1 (x[a][r]), qv, x[a][r]);
    }
    #pragma unroll
    for (int a = 0; a < NA; a++){
        #pragma unroll
        for (int r = 0; r < 4; r++) x[a][r] = fmaf(lxor2 (x[a][r]), qv, x[a][r]);
    }
    #pragma unroll
    for (int a = 0; a < NA; a++){
        #pragma unroll
        for (int r = 0; r < 4; r++) x[a][r] = fmaf(lxor8 (x[a][r]), qv, x[a][r]);
    }
    #pragma unroll
    for (int a = 0; a < NA; a++){
        #pragma unroll
        for (int r = 0; r < 4; r++) x[a][r] = fmaf(lxor4 (x[a][r]), qv, x[a][r]);
    }
    #pragma unroll
    for (int a = 0; a < NA; a++){
        #pragma unroll
        for (int r = 0; r < 4; r++) x[a][r] = fmaf(lxor16(x[a][r]), qv, x[a][r]);
    }
    #pragma unroll
    for (int a = 0; a < NA; a++){
        #pragma unroll
        for (int r = 0; r < 4; r++) x[a][r] = fmaf(lxor32(x[a][r]), qv, x[a][r]);
    }
    #pragma unroll
    for (int a = 0; a < NA; a++){
        float t0 = x[a][0], t2 = x[a][2];
        x[a][0] = fmaf(QF, x[a][1], x[a][0]);
        x[a][1] = fmaf(QF, t0,      x[a][1]);
        x[a][2] = fmaf(QF, x[a][3], x[a][2]);
        x[a][3] = fmaf(QF, t2,      x[a][3]);
        t0 = x[a][0]; float t1 = x[a][1];
        x[a][0] = fmaf(QF, x[a][2], x[a][0]);
        x[a][1] = fmaf(QF, x[a][3], x[a][1]);
        x[a][2] = fmaf(QF, t0,      x[a][2]);
        x[a][3] = fmaf(QF, t1,      x[a][3]);
    }
}

/* ---- prep: blocks 0..31 transpose Ws -> WsT[512][256];
       block 32: iteration-0 peel constants X,P0,phi0 [32][256] (batch-independent) ---- */
__global__ __launch_bounds__(256) void prep_kernel(
        const float* __restrict__ Ws,    const float* __restrict__ psiA0,
        const float* __restrict__ psiP0, const float* __restrict__ p_alpha,
        const float* __restrict__ p_msq, const float* __restrict__ p_pw,
        const float* __restrict__ p_iw,  const float* __restrict__ p_evo,
        float* __restrict__ WsT,  float* __restrict__ Xc,  float* __restrict__ P0c,
        float* __restrict__ F0c)
{
    if (blockIdx.x < 32){
        __shared__ float tile[64][65];
        const int rt = blockIdx.x & 3, ct = blockIdx.x >> 2;
        const int r0 = rt*64, c0t = ct*64;
        const int tx = threadIdx.x & 63, ty = threadIdx.x >> 6;
        #pragma unroll
        for (int k = 0; k < 16; k++){
            const int row = ty*16 + k;
            tile[row][tx] = Ws[(r0+row)*512 + c0t + tx];
        }
        __syncthreads();
        #pragma unroll
        for (int k = 0; k < 16; k++){
            const int row = ty*16 + k;
            WsT[(c0t+row)*256 + r0 + tx] = tile[tx][row];
        }
        return;
    }
    /* block 32: batch-independent iteration-0 dynamics */
    const int tid = threadIdx.x;
    const int w = tid >> 6, l = tid & 63;
    const float alpha = p_alpha[0], msq = p_msq[0], pw = p_pw[0], iw = p_iw[0];
    const float dt   = 1.0f / (1.0f + __expf(-p_evo[0]));
    const float dta  = dt * alpha * INV255;
    const float dtpw = dt * pw * INV255;
    const float c0   = 1.0f - dt * (msq + iw);
    const float m0 = (l == 0) ? 0.0f : 1.0f;
    int nn[4]; float krow[4];
    float c18;
    { const float t1 = 1.0f + QF, t2 = t1*t1, t4 = t2*t2; c18 = t4*t4; }
    #pragma unroll
    for (int r = 0; r < 4; r++){
        nn[r] = l + 64*r;
        krow[r] = c18 - __expf(-0.125f * (float)__popc(nn[r]));
    }
    #pragma unroll
    for (int dd = 0; dd < 8; dd++){
        const int d = w*8 + dd;
        float A0[4], ph0[4], sp[4], cp[4];
        float x[5][4];
        #pragma unroll
        for (int r = 0; r < 4; r++){
            const int n = nn[r];
            A0[r]  = (n > 0) ? softplus_f(psiA0[(n-1)*32 + d]) : 0.0f;
            ph0[r] = (n > 0) ? psiP0[(n-1)*32 + d] : 0.0f;
            sp[r] = __sinf(ph0[r]); cp[r] = __cosf(ph0[r]);
            const float mk = (r == 0) ? m0 : 1.0f;
            const float xa = A0[r] * mk;
            x[0][r] = xa;
            x[1][r] = sp[r] * mk;
            x[2][r] = cp[r] * mk;
            x[3][r] = xa * cp[r];
            x[4][r] = xa * sp[r];
        }
        bflyN<5>(x);
        #pragma unroll
        for (int r = 0; r < 4; r++){
            const float Ao   = A0[r];
            const float lapp = fmaf(-krow[r], Ao, x[0][r]);
            const float Vp   = fmaf(cp[r], x[3][r], sp[r]*x[4][r]);
            const float Pp   = fmaf(-sp[r], x[2][r], cp[r]*x[1][r]);
            float X = c0 * Ao;
            X = fmaf(dta,  lapp, X);
            X = fmaf(dtpw, Vp,   X);
            const int idx = d*256 + nn[r];
            Xc[idx]  = X;
            P0c[idx] = dta * Ao * Pp;
            F0c[idx] = ph0[r];
        }
    }
}

/* ---------------- fused kernel: one block = one batch element, 512 threads (8 waves).
   INVERTED register tenancy vs R3-R8: the loop-INVARIANT drive {CAp,Pin} (32 f32)
   lives in REGISTERS (written once, read-only -> ideal tenants); the MUTATED state
   {A,phi} streams through LDS own-slot (RMW per dd: 4 ds_read_b64 -> compute ->
   4 ds_write_b64). Structural live set ~95 <= cap-128 -> no scratch (R3/R6: ~150
   live -> 65MB scratch; R9: clean but 1024-thr blocks never co-reside).
   Norm-clip becomes a CARRIED SCALE scl_c[r] applied at next load — bitwise
   identical (stored A is pre-clip; rr uses pre-clip An per reference).
   LDS 77KB -> 2 blocks/CU = 16 waves/CU with barrier overlap (the R3 advantage).
   drive identity: Dsp*cos(phi) - Dcp*sin(phi) == CAp * sin(Pin - phi).
   peel-0 + 3 full iters + peel-4 ------- */
template<bool USET>
__global__ __launch_bounds__(512, 4) void fused_kernel(
        const float* __restrict__ ns,     /* [B][512] */
        const float* __restrict__ Ws,     /* [256][512] */
        const float* __restrict__ WsT,    /* [512][256] or null */
        const float* __restrict__ bs,     /* [256] */
        const float* __restrict__ WA,     /* [32][32] */
        const float* __restrict__ bA,     /* [32] */
        const float* __restrict__ WP,     /* [32][32] */
        const float* __restrict__ bP,     /* [32] */
        const float* __restrict__ psiA0,  /* [255*32] */
        const float* __restrict__ psiP0,  /* [255*32] */
        const float* __restrict__ Xc,     /* [32][256] or null */
        const float* __restrict__ P0c,    /* [32][256] or null */
        const float* __restrict__ F0c,    /* [32][256] or null */
        const float* __restrict__ Wcomp,  /* [32*255] */
        const float* __restrict__ bcomp,  /* [32] */
        const float* __restrict__ Wread,  /* [64*1024] */
        const float* __restrict__ bread,  /* [64] */
        const float* __restrict__ p_alpha, const float* __restrict__ p_msq,
        const float* __restrict__ p_pw,    const float* __restrict__ p_iw,
        const float* __restrict__ p_evo,   const float* __restrict__ p_pcpl,
        float* __restrict__ out, int Bb)
{
    /* 77 KB total -> 2 blocks/CU (16 waves/CU) */
    __shared__ __align__(16) float2 ST[16][512];    /* 64 KB: {A, phi} per (k=dd*4+r, tid) — own-slot, no sync */
    __shared__ __align__(16) float  red[2048];      /* 8 KB: GEMV/norm partials; aliased ac/rop at readout */
    __shared__ __align__(16) float  hA[256];
    __shared__ __align__(16) float  hP[256];
    __shared__ __align__(16) float  nsb[512];
    __shared__ __align__(16) float  fe[256];

    float* ac  = red;          /* [1024] readout stage 1 (red dead by then) */
    float* rop = red + 1024;   /* [512]  readout stage 2 */

    const int b   = blockIdx.x;
    const int tid = threadIdx.x;
    const int w   = tid >> 6, l = tid & 63;

    const float alpha = p_alpha[0], msq = p_msq[0], pw = p_pw[0], iw = p_iw[0];
    const float pcpl  = p_pcpl[0];
    const float dt    = 1.0f / (1.0f + __expf(-p_evo[0]));
    const float dta  = dt * alpha * INV255;
    const float dtpw = dt * pw * INV255;
    const float c0   = 1.0f - dt * (msq + iw);
    const float dtiw = dt * iw;

    /* ---- front-end: fe[f] = ns[b]·Ws_row(f) + bs[f]; 512 threads, 2 partials per f (R6 form) ---- */
    nsb[tid] = ns[b*512 + tid];
    __syncthreads();
    {
        const int k = tid >> 1, part = tid & 1;
        float f = (part == 0) ? bs[k] : 0.0f;
        if (USET){
            const float4* nb4 = (const float4*)nsb + part*64;
            const float*  colb = WsT + (part*64)*1024 + k;
            #pragma unroll 8
            for (int j4 = 0; j4 < 64; j4++){
                const float4 nv = nb4[j4];
                const float* col = colb + j4*1024;
                f = fmaf(col[0],   nv.x, f);
                f = fmaf(col[256], nv.y, f);
                f = fmaf(col[512], nv.z, f);
                f = fmaf(col[768], nv.w, f);
            }
        } else {
            const float4* wr  = (const float4*)(Ws + k*512) + part*64;
            const float4* nb4 = (const float4*)nsb + part*64;
            #pragma unroll 8
            for (int i = 0; i < 64; i++){
                const float4 wv = wr[i], nv = nb4[i];
                f = fmaf(wv.x, nv.x, f); f = fmaf(wv.y, nv.y, f);
                f = fmaf(wv.z, nv.z, f); f = fmaf(wv.w, nv.w, f);
            }
        }
        red[part*256 + k] = f;
    }
    __syncthreads();
    if (tid < 256) fe[tid] = red[tid] + red[256 + tid];
    __syncthreads();
    {   /* fold through W_A / W_phi (linearity of the member-mean); low waves -> hA, high -> hP */
        const int t2 = tid & 255;
        const int s = t2 >> 5, d2 = t2 & 31;
        const float* Wm = (tid < 256) ? WA : WP;
        float acc = 0.0f;
        #pragma unroll 8
        for (int dp = 0; dp < 32; dp++)
            acc = fmaf(Wm[d2*32 + dp], fe[s*32 + dp], acc);
        if (tid < 256) hA[t2] = acc; else hP[t2] = acc;
    }
    __syncthreads();

    /* per-thread clique constants: n = l + 64r */
    int   nn[4];
    float krow[4];
    const float m0 = (l == 0) ? 0.0f : 1.0f;
    float c18;
    { const float t1 = 1.0f + QF, t2 = t1*t1, t4 = t2*t2; c18 = t4*t4; }
    #pragma unroll
    for (int r = 0; r < 4; r++){
        nn[r] = l + 64*r;
        krow[r] = c18 - __expf(-0.125f * (float)__popc(nn[r]));
    }

    /* drive terms in REGS (loop-invariant); state {A,phi} -> LDS own-slot.
       scl_c = carried norm-clip scale (applied at next load). */
    float CAp[4][4], Pin[4][4];
    float scl_c[4] = {1.0f, 1.0f, 1.0f, 1.0f};
    float nrm0[4] = {0.f, 0.f, 0.f, 0.f};

    #pragma unroll
    for (int dd = 0; dd < 4; dd++){
        const int d = w*4 + dd;
        const float bAd = bA[d], bPd = bP[d];
        float gA_[8], gP_[8];
        #pragma unroll
        for (int s = 0; s < 8; s++){ gA_[s] = hA[s*32 + d]; gP_[s] = hP[s*32 + d]; }
        #pragma unroll
        for (int r = 0; r < 4; r++){
            const int pop = __popc(nn[r]);
            const float rdep = 1.0f / (float)(pop ? pop : 1);
            float sA = 0.0f, sP = 0.0f;
            #pragma unroll
            for (int s = 0; s < 8; s++){
                if ((nn[r] >> s) & 1){ sA += gA_[s]; sP += gP_[s]; }
            }
            const float uA  = fmaf(sA, rdep, bAd);
            const float uP  = fmaf(sP, rdep, bPd);
            const float Ain = softplus_f(uA);
            const float pin = PI_F * tanh_fast(uP);
            const float ca = dtiw * Ain;
            CAp[dd][r] = ca; Pin[dd][r] = pin;
            if (USET){
                /* iter-0 peel: A1 = softplus(X + ca); phi1 = F0 + P0/A1 + ca*sin(pin-F0) */
                const int idx = d*256 + nn[r];
                const float An = softplus_f(Xc[idx] + ca);
                const float rr = __builtin_amdgcn_rcpf(An + 1e-8f);
                const float F0 = F0c[idx];
                float pb = fmaf(ca, __sinf(pin - F0), F0);
                ST[dd*4 + r][tid] = make_float2(An, fmaf(P0c[idx], rr, pb));
                nrm0[r] = fmaf(An, An, nrm0[r]);
            } else {
                const int nm1 = (nn[r] > 0) ? (nn[r] - 1) : 0;
                ST[dd*4 + r][tid] = make_float2(softplus_f(psiA0[nm1*32 + d]),
                                                psiP0[nm1*32 + d]);
            }
        }
        __builtin_amdgcn_sched_barrier(0);
    }

    if (USET){
        /* norm-clip for peeled iteration 0 -> carried scale only (no multiply) */
        #pragma unroll
        for (int r = 0; r < 4; r++) red[w*256 + nn[r]] = nrm0[r];
        __syncthreads();
        #pragma unroll
        for (int r = 0; r < 4; r++){
            const int n = nn[r];
            const float t = red[n]        + red[256 + n]  + red[512 + n]  + red[768 + n]
                          + red[1024 + n] + red[1280 + n] + red[1536 + n] + red[1792 + n];
            scl_c[r] = (t > 1.0f) ? rsqrtf(t) : 1.0f;
        }
        __syncthreads();   /* protect red against next writer */
    }

    /* ---- full iterations (3 when peeled, 4 otherwise) ---- */
    const int NFULL = USET ? 3 : 4;
    for (int it = 0; it < NFULL; it++){
        float nrm[4] = {0.f, 0.f, 0.f, 0.f};
        #pragma unroll
        for (int dd = 0; dd < 4; dd++){
            float Al[4], ph[4], sp[4], cp[4];
            #pragma unroll
            for (int r = 0; r < 4; r++){
                const float2 st = ST[dd*4 + r][tid];
                Al[r] = st.x * scl_c[r];     /* apply carried clip scale */
                ph[r] = st.y;
            }
            float x[5][4];
            {
                sp[0] = __sinf(ph[0]); cp[0] = __cosf(ph[0]);
                const float xa = Al[0] * m0;
                x[0][0] = xa;
                x[1][0] = sp[0] * m0;
                x[2][0] = cp[0] * m0;
                x[3][0] = xa * cp[0];
                x[4][0] = xa * sp[0];
            }
            #pragma unroll
            for (int r = 1; r < 4; r++){
                sp[r] = __sinf(ph[r]); cp[r] = __cosf(ph[r]);
                const float xa = Al[r];
                x[0][r] = xa;
                x[1][r] = sp[r];
                x[2][r] = cp[r];
                x[3][r] = xa * cp[r];
                x[4][r] = xa * sp[r];
            }
            bflyN<5>(x);
            #pragma unroll
            for (int r = 0; r < 4; r++){
                const float Ao   = Al[r];
                const float lapp = fmaf(-krow[r], Ao, x[0][r]);
                const float Vp   = fmaf(cp[r], x[3][r], sp[r]*x[4][r]);
                float Aarg = fmaf(c0, Ao, CAp[dd][r]);
                Aarg = fmaf(dta,  lapp, Aarg);
                Aarg = fmaf(dtpw, Vp,   Aarg);
                const float An = softplus_f(Aarg);
                const float Pp = fmaf(-sp[r], x[2][r], cp[r]*x[1][r]);
                const float rr = __builtin_amdgcn_rcpf(An + 1e-8f);
                const float sdr = __sinf(Pin[dd][r] - ph[r]);
                float pb = fmaf(CAp[dd][r], sdr, ph[r]);
                ST[dd*4 + r][tid] = make_float2(An, fmaf(dta*Ao, Pp*rr, pb));
                nrm[r] = fmaf(An, An, nrm[r]);
            }
            __builtin_amdgcn_sched_barrier(0);
        }
        #pragma unroll
        for (int r = 0; r < 4; r++) red[w*256 + nn[r]] = nrm[r];
        __syncthreads();
        #pragma unroll
        for (int r = 0; r < 4; r++){
            const int n = nn[r];
            const float t = red[n]        + red[256 + n]  + red[512 + n]  + red[768 + n]
                          + red[1024 + n] + red[1280 + n] + red[1536 + n] + red[1792 + n];
            scl_c[r] = (t > 1.0f) ? rsqrtf(t) : 1.0f;
        }
        __syncthreads();   /* protect red against next iteration's writer */
    }

    /* ---- final iteration (peeled): phi-update dead -> 3-array butterfly, A-only epilogue ---- */
    {
        float nrm[4] = {0.f, 0.f, 0.f, 0.f};
        #pragma unroll
        for (int dd = 0; dd < 4; dd++){
            float Al[4], ph[4], sp[4], cp[4];
            #pragma unroll
            for (int r = 0; r < 4; r++){
                const float2 st = ST[dd*4 + r][tid];
                Al[r] = st.x * scl_c[r];
                ph[r] = st.y;
            }
            float y[3][4];
            {
                sp[0] = __sinf(ph[0]); cp[0] = __cosf(ph[0]);
                const float xa = Al[0] * m0;
                y[0][0] = xa;
                y[1][0] = xa * cp[0];
                y[2][0] = xa * sp[0];
            }
            #pragma unroll
            for (int r = 1; r < 4; r++){
                sp[r] = __sinf(ph[r]); cp[r] = __cosf(ph[r]);
                const float xa = Al[r];
                y[0][r] = xa;
                y[1][r] = xa * cp[r];
                y[2][r] = xa * sp[r];
            }
            bflyN<3>(y);
            #pragma unroll
            for (int r = 0; r < 4; r++){
                const float Ao   = Al[r];
                const float lapp = fmaf(-krow[r], Ao, y[0][r]);
                const float Vp   = fmaf(cp[r], y[1][r], sp[r]*y[2][r]);
                float Aarg = fmaf(c0, Ao, CAp[dd][r]);
                Aarg = fmaf(dta,  lapp, Aarg);
                Aarg = fmaf(dtpw, Vp,   Aarg);
                const float An = softplus_f(Aarg);
                ST[dd*4 + r][tid] = make_float2(An, 0.0f);
                nrm[r] = fmaf(An, An, nrm[r]);
            }
            __builtin_amdgcn_sched_barrier(0);
        }
        #pragma unroll
        for (int r = 0; r < 4; r++) red[w*256 + nn[r]] = nrm[r];
        __syncthreads();
        #pragma unroll
        for (int r = 0; r < 4; r++){
            const int n = nn[r];
            const float t = red[n]        + red[256 + n]  + red[512 + n]  + red[768 + n]
                          + red[1024 + n] + red[1280 + n] + red[1536 + n] + red[1792 + n];
            scl_c[r] = (t > 1.0f) ? rsqrtf(t) : 1.0f;
        }
        __syncthreads();   /* red is about to be reused as ac[] */
    }

    /* ---- readout: preload final A (apply carried scale + n==0 kill), then DPP wave-sums ---- */
    float Ar[4][4];
    #pragma unroll
    for (int dd = 0; dd < 4; dd++){
        #pragma unroll
        for (int r = 0; r < 4; r++)
            Ar[dd][r] = ST[dd*4 + r][tid].x * scl_c[r];
        Ar[dd][0] *= m0;   /* kill n==0 slot */
    }

    for (int c = 0; c < 32; c++){
        float wv[4];
        #pragma unroll
        for (int r = 0; r < 4; r++){
            const int idx = c*255 + nn[r] - 1;
            wv[r] = Wcomp[idx < 0 ? 0 : idx];
        }
        const float bc = bcomp[c];
        #pragma unroll
        for (int dd = 0; dd < 4; dd++){
            float v = wv[0] * Ar[dd][0];
            v = fmaf(wv[1], Ar[dd][1], v);
            v = fmaf(wv[2], Ar[dd][2], v);
            v = fmaf(wv[3], Ar[dd][3], v);
            v = wave_sum63(v);
            if (l == 63)
                ac[(w*4 + dd)*32 + c] = fmaxf(v + bc, 0.0f);
        }
    }
    __syncthreads();

    /* ro[k] = sum_j Wread[k][j] * ac[j] + bread[k]; k = 0..63 split over 4 partials */
    {
        const int k = tid >> 2, part = tid & 3;
        const float4* Wr4 = (const float4*)Wread + k*256;
        const float4* ac4 = (const float4*)ac;
        float s = 0.0f;
        #pragma unroll 4
        for (int jj = 0; jj < 64; jj++){
            const int j4 = part + 4*jj;
            const float4 wv = Wr4[j4];
            const float4 av = ac4[j4];
            s = fmaf(wv.x, av.x, s); s = fmaf(wv.y, av.y, s);
            s = fmaf(wv.z, av.z, s); s = fmaf(wv.w, av.w, s);
        }
        rop[tid] = s;
    }
    __syncthreads();
    if (tid < 32){
        const float ra = rop[tid*4] + rop[tid*4+1] + rop[tid*4+2] + rop[tid*4+3] + bread[tid];
        const int   t2 = tid + 32;
        const float rp = rop[t2*4] + rop[t2*4+1] + rop[t2*4+2] + rop[t2*4+3] + bread[t2];
        const float amp = softplus_f(ra);
        const float ph  = PI_F * tanhf(rp * pcpl);
        const float cph = __cosf(ph);
        /* PLANAR output (verified R7): chunk0 = Re(psi), chunk1 = amplitude, chunk2 = phase */
        const int o = b*32 + tid;
        out[o]         = amp * cph;   /* Re(psi) */
        out[Bb*32 + o] = amp;         /* amplitude */
        out[Bb*64 + o] = ph;          /* phase */
    }
}

extern "C" void kernel_launch(void* const* d_in, const int* in_sizes, int n_in,
                              void* d_out, int out_size, void* d_ws, size_t ws_size,
                              hipStream_t stream) {
    const float* ns      = (const float*)d_in[0];   /* [B][512] */
    const float* Ws      = (const float*)d_in[1];   /* [256][512] */
    const float* bs      = (const float*)d_in[2];   /* [256] */
    const float* WA      = (const float*)d_in[3];   /* [32][32] */
    const float* bA      = (const float*)d_in[4];   /* [32] */
    const float* WP      = (const float*)d_in[5];   /* [32][32] */
    const float* bP      = (const float*)d_in[6];   /* [32] */
    const float* psiA0   = (const float*)d_in[7];   /* [255*32] */
    const float* psiP0   = (const float*)d_in[8];   /* [255*32] */
    const float* Wcomp   = (const float*)d_in[9];   /* [32*255] */
    const float* bcomp   = (const float*)d_in[10];  /* [32] */
    const float* Wread   = (const float*)d_in[11];  /* [64*1024] */
    const float* bread   = (const float*)d_in[12];  /* [64] */
    const float* p_alpha = (const float*)d_in[13];
    const float* p_msq   = (const float*)d_in[14];
    const float* p_pw    = (const float*)d_in[15];
    const float* p_iw    = (const float*)d_in[16];
    const float* p_evo   = (const float*)d_in[17];
    const float* p_pcpl  = (const float*)d_in[18];

    const int Bb = in_sizes[0] / 512;               /* 1024 */

    const size_t need = (size_t)(512*256 + 3*32*256) * sizeof(float);
    if (ws_size >= need){
        float* WsT = (float*)d_ws;                  /* [512][256] */
        float* Xc  = WsT + 512*256;                 /* [32][256] each */
        float* P0c = Xc  + 32*256;
        float* F0c = P0c + 32*256;
        prep_kernel<<<33, 256, 0, stream>>>(Ws, psiA0, psiP0,
                                            p_alpha, p_msq, p_pw, p_iw, p_evo,
                                            WsT, Xc, P0c, F0c);
        fused_kernel<true><<<Bb, 512, 0, stream>>>(ns, Ws, WsT, bs, WA, bA, WP, bP,
                                                   psiA0, psiP0, Xc, P0c, F0c,
                                                   Wcomp, bcomp, Wread, bread,
                                                   p_alpha, p_msq, p_pw, p_iw,
                                                   p_evo, p_pcpl, (float*)d_out, Bb);
    } else {
        fused_kernel<false><<<Bb, 512, 0, stream>>>(ns, Ws, nullptr, bs, WA, bA, WP, bP,
                                                    psiA0, psiP0,
                                                    nullptr, nullptr, nullptr,
                                                    Wcomp, bcomp, Wread, bread,
                                                    p_alpha, p_msq, p_pw, p_iw,
                                                    p_evo, p_pcpl, (float*)d_out, Bb);
    }
}

// Round 11
// 284.125 us; speedup vs baseline: 1.1927x; 1.0069x over previous
//
#include <hip/hip_runtime.h>
#include <math.h>

#define PI_F   3.14159265358979f
#define QF     0.88249690258459546f   /* exp(-1/8) */
#define INV255 (1.0f/255.0f)

__device__ __forceinline__ float softplus_f(float x){
    return fmaxf(x, 0.0f) + __logf(1.0f + __expf(-fabsf(x)));
}
__device__ __forceinline__ float tanh_fast(float x){
    const float e = __expf(2.0f*x);
    return fmaf(-2.0f, __builtin_amdgcn_rcpf(e + 1.0f), 1.0f);
}

/* ---- lane exchanges (all HW-verified equivalent R1==R2; row_ror:8 verified R11) ---- */
template<int CTRL>
__device__ __forceinline__ float dppmov(float x){
    return __int_as_float(__builtin_amdgcn_mov_dpp(__float_as_int(x), CTRL, 0xF, 0xF, false));
}
__device__ __forceinline__ float lxor1 (float x){ return dppmov<0xB1>(x);  }  /* quad_perm(1,0,3,2) */
__device__ __forceinline__ float lxor2 (float x){ return dppmov<0x4E>(x);  }  /* quad_perm(2,3,0,1) */
__device__ __forceinline__ float lxor8 (float x){ return dppmov<0x128>(x); }  /* row_ror:8 == i^8   */
__device__ __forceinline__ float lxor4 (float x){ return __int_as_float(__builtin_amdgcn_ds_swizzle(__float_as_int(x), 0x101F)); }
__device__ __forceinline__ float lxor16(float x){ return __int_as_float(__builtin_amdgcn_ds_swizzle(__float_as_int(x), 0x401F)); }
__device__ __forceinline__ float lxor32(float x){ return __shfl_xor(x, 32, 64); }

template<int CTRL>
__device__ __forceinline__ float dppadd(float v){
    return v + __int_as_float(__builtin_amdgcn_update_dpp(0, __float_as_int(v), CTRL, 0xF, 0xF, true));
}
/* full 64-lane sum, result valid in lane 63 (verified R11) */
__device__ __forceinline__ float wave_sum63(float v){
    v = dppadd<0x111>(v);   /* row_shr:1  */
    v = dppadd<0x112>(v);   /* row_shr:2  */
    v = dppadd<0x114>(v);   /* row_shr:4  */
    v = dppadd<0x118>(v);   /* row_shr:8  */
    v = dppadd<0x142>(v);   /* row_bcast:15 */
    v = dppadd<0x143>(v);   /* row_bcast:31 */
    return v;
}

/* Weighted-Hadamard butterfly, bits 0..5 on lanes, 6..7 on regs. Stages commute. */
template<int NA>
__device__ __forceinline__ void bflyN(float (&x)[NA][4]){
    const float qv = QF;
    #pragma unroll
    for (int a = 0; a < NA; a++){
        #pragma unroll
        for (int r = 0; r < 4; r++) x[a][r] = fmaf(lxor1 (x[a][r]), qv, x[a][r]);
    }
    #pragma unroll
    for (int a = 0; a < NA; a++){
        #pragma unroll
        for (int r = 0; r < 4; r++) x[a][r] = fmaf(lxor2 (x[a][r]), qv, x[a][r]);
    }
    #pragma unroll
    for (int a = 0; a < NA; a++){
        #pragma unroll
        for (int r = 0; r < 4; r++) x[a][r] = fmaf(lxor8 (x[a][r]), qv, x[a][r]);
    }
    #pragma unroll
    for (int a = 0; a < NA; a++){
        #pragma unroll
        for (int r = 0; r < 4; r++) x[a][r] = fmaf(lxor4 (x[a][r]), qv, x[a][r]);
    }
    #pragma unroll
    for (int a = 0; a < NA; a++){
        #pragma unroll
        for (int r = 0; r < 4; r++) x[a][r] = fmaf(lxor16(x[a][r]), qv, x[a][r]);
    }
    #pragma unroll
    for (int a = 0; a < NA; a++){
        #pragma unroll
        for (int r = 0; r < 4; r++) x[a][r] = fmaf(lxor32(x[a][r]), qv, x[a][r]);
    }
    #pragma unroll
    for (int a = 0; a < NA; a++){
        float t0 = x[a][0], t2 = x[a][2];
        x[a][0] = fmaf(QF, x[a][1], x[a][0]);
        x[a][1] = fmaf(QF, t0,      x[a][1]);
        x[a][2] = fmaf(QF, x[a][3], x[a][2]);
        x[a][3] = fmaf(QF, t2,      x[a][3]);
        t0 = x[a][0]; float t1 = x[a][1];
        x[a][0] = fmaf(QF, x[a][2], x[a][0]);
        x[a][1] = fmaf(QF, x[a][3], x[a][1]);
        x[a][2] = fmaf(QF, t0,      x[a][2]);
        x[a][3] = fmaf(QF, t1,      x[a][3]);
    }
}

/* ---- prep: blocks 0..31 transpose Ws -> WsT[512][256];
       block 32: iteration-0 peel constants X,P0,phi0 [32][256] (batch-independent) ---- */
__global__ __launch_bounds__(256) void prep_kernel(
        const float* __restrict__ Ws,    const float* __restrict__ psiA0,
        const float* __restrict__ psiP0, const float* __restrict__ p_alpha,
        const float* __restrict__ p_msq, const float* __restrict__ p_pw,
        const float* __restrict__ p_iw,  const float* __restrict__ p_evo,
        float* __restrict__ WsT,  float* __restrict__ Xc,  float* __restrict__ P0c,
        float* __restrict__ F0c)
{
    if (blockIdx.x < 32){
        __shared__ float tile[64][65];
        const int rt = blockIdx.x & 3, ct = blockIdx.x >> 2;
        const int r0 = rt*64, c0t = ct*64;
        const int tx = threadIdx.x & 63, ty = threadIdx.x >> 6;
        #pragma unroll
        for (int k = 0; k < 16; k++){
            const int row = ty*16 + k;
            tile[row][tx] = Ws[(r0+row)*512 + c0t + tx];
        }
        __syncthreads();
        #pragma unroll
        for (int k = 0; k < 16; k++){
            const int row = ty*16 + k;
            WsT[(c0t+row)*256 + r0 + tx] = tile[tx][row];
        }
        return;
    }
    /* block 32: batch-independent iteration-0 dynamics */
    const int tid = threadIdx.x;
    const int w = tid >> 6, l = tid & 63;
    const float alpha = p_alpha[0], msq = p_msq[0], pw = p_pw[0], iw = p_iw[0];
    const float dt   = 1.0f / (1.0f + __expf(-p_evo[0]));
    const float dta  = dt * alpha * INV255;
    const float dtpw = dt * pw * INV255;
    const float c0   = 1.0f - dt * (msq + iw);
    const float m0 = (l == 0) ? 0.0f : 1.0f;
    int nn[4]; float krow[4];
    float c18;
    { const float t1 = 1.0f + QF, t2 = t1*t1, t4 = t2*t2; c18 = t4*t4; }
    #pragma unroll
    for (int r = 0; r < 4; r++){
        nn[r] = l + 64*r;
        krow[r] = c18 - __expf(-0.125f * (float)__popc(nn[r]));
    }
    #pragma unroll
    for (int dd = 0; dd < 8; dd++){
        const int d = w*8 + dd;
        float A0[4], ph0[4], sp[4], cp[4];
        float x[5][4];
        #pragma unroll
        for (int r = 0; r < 4; r++){
            const int n = nn[r];
            A0[r]  = (n > 0) ? softplus_f(psiA0[(n-1)*32 + d]) : 0.0f;
            ph0[r] = (n > 0) ? psiP0[(n-1)*32 + d] : 0.0f;
            sp[r] = __sinf(ph0[r]); cp[r] = __cosf(ph0[r]);
            const float mk = (r == 0) ? m0 : 1.0f;
            const float xa = A0[r] * mk;
            x[0][r] = xa;
            x[1][r] = sp[r] * mk;
            x[2][r] = cp[r] * mk;
            x[3][r] = xa * cp[r];
            x[4][r] = xa * sp[r];
        }
        bflyN<5>(x);
        #pragma unroll
        for (int r = 0; r < 4; r++){
            const float Ao   = A0[r];
            const float lapp = fmaf(-krow[r], Ao, x[0][r]);
            const float Vp   = fmaf(cp[r], x[3][r], sp[r]*x[4][r]);
            const float Pp   = fmaf(-sp[r], x[2][r], cp[r]*x[1][r]);
            float X = c0 * Ao;
            X = fmaf(dta,  lapp, X);
            X = fmaf(dtpw, Vp,   X);
            const int idx = d*256 + nn[r];
            Xc[idx]  = X;
            P0c[idx] = dta * Ao * Pp;
            F0c[idx] = ph0[r];
        }
    }
}

/* ---------------- fused kernel: one block = one batch element, 512 threads (8 waves).
   R10 WINNER structure (202us, VGPR 52, zero spill): loop-invariant drive in REGS,
   mutated {A,phi} streams through own-slot LDS (ST is a software-managed spill area
   — only the owning thread touches its slots). 77KB LDS -> 2 blocks/CU overlap.
   R11 adds two refinements:
   (1) one-dd-ahead ST PREFETCH (stn[4]): ds_read_b64 issued at top of current dd
       body / before the norm barriers, consumed next dd -> hides LDS latency that
       sched_barrier(0) otherwise exposes at each dd head.
   (2) Pin -> {Dsp,Dcp} = ca*sin/cos(Pin) (R0's HW-verified form): drive term
       becomes Dsp*cp - Dcp*sp (2 fma on existing sp/cp) instead of sub+__sinf
       (serial trans op). -16 trans/iter, +16 invariant regs (~105 live <= 128).
   peel-0 + 3 full iters + peel-4; carried norm-clip scale scl_c. ------- */
template<bool USET>
__global__ __launch_bounds__(512, 4) void fused_kernel(
        const float* __restrict__ ns,     /* [B][512] */
        const float* __restrict__ Ws,     /* [256][512] */
        const float* __restrict__ WsT,    /* [512][256] or null */
        const float* __restrict__ bs,     /* [256] */
        const float* __restrict__ WA,     /* [32][32] */
        const float* __restrict__ bA,     /* [32] */
        const float* __restrict__ WP,     /* [32][32] */
        const float* __restrict__ bP,     /* [32] */
        const float* __restrict__ psiA0,  /* [255*32] */
        const float* __restrict__ psiP0,  /* [255*32] */
        const float* __restrict__ Xc,     /* [32][256] or null */
        const float* __restrict__ P0c,    /* [32][256] or null */
        const float* __restrict__ F0c,    /* [32][256] or null */
        const float* __restrict__ Wcomp,  /* [32*255] */
        const float* __restrict__ bcomp,  /* [32] */
        const float* __restrict__ Wread,  /* [64*1024] */
        const float* __restrict__ bread,  /* [64] */
        const float* __restrict__ p_alpha, const float* __restrict__ p_msq,
        const float* __restrict__ p_pw,    const float* __restrict__ p_iw,
        const float* __restrict__ p_evo,   const float* __restrict__ p_pcpl,
        float* __restrict__ out, int Bb)
{
    /* 77 KB total -> 2 blocks/CU (16 waves/CU) */
    __shared__ __align__(16) float2 ST[16][512];    /* 64 KB: {A, phi} per (k=dd*4+r, tid) — own-slot, no sync */
    __shared__ __align__(16) float  red[2048];      /* 8 KB: GEMV/norm partials; aliased ac/rop at readout */
    __shared__ __align__(16) float  hA[256];
    __shared__ __align__(16) float  hP[256];
    __shared__ __align__(16) float  nsb[512];
    __shared__ __align__(16) float  fe[256];

    float* ac  = red;          /* [1024] readout stage 1 (red dead by then) */
    float* rop = red + 1024;   /* [512]  readout stage 2 */

    const int b   = blockIdx.x;
    const int tid = threadIdx.x;
    const int w   = tid >> 6, l = tid & 63;

    const float alpha = p_alpha[0], msq = p_msq[0], pw = p_pw[0], iw = p_iw[0];
    const float pcpl  = p_pcpl[0];
    const float dt    = 1.0f / (1.0f + __expf(-p_evo[0]));
    const float dta  = dt * alpha * INV255;
    const float dtpw = dt * pw * INV255;
    const float c0   = 1.0f - dt * (msq + iw);
    const float dtiw = dt * iw;

    /* ---- front-end: fe[f] = ns[b]·Ws_row(f) + bs[f]; 512 threads, 2 partials per f (R6 form) ---- */
    nsb[tid] = ns[b*512 + tid];
    __syncthreads();
    {
        const int k = tid >> 1, part = tid & 1;
        float f = (part == 0) ? bs[k] : 0.0f;
        if (USET){
            const float4* nb4 = (const float4*)nsb + part*64;
            const float*  colb = WsT + (part*64)*1024 + k;
            #pragma unroll 8
            for (int j4 = 0; j4 < 64; j4++){
                const float4 nv = nb4[j4];
                const float* col = colb + j4*1024;
                f = fmaf(col[0],   nv.x, f);
                f = fmaf(col[256], nv.y, f);
                f = fmaf(col[512], nv.z, f);
                f = fmaf(col[768], nv.w, f);
            }
        } else {
            const float4* wr  = (const float4*)(Ws + k*512) + part*64;
            const float4* nb4 = (const float4*)nsb + part*64;
            #pragma unroll 8
            for (int i = 0; i < 64; i++){
                const float4 wv = wr[i], nv = nb4[i];
                f = fmaf(wv.x, nv.x, f); f = fmaf(wv.y, nv.y, f);
                f = fmaf(wv.z, nv.z, f); f = fmaf(wv.w, nv.w, f);
            }
        }
        red[part*256 + k] = f;
    }
    __syncthreads();
    if (tid < 256) fe[tid] = red[tid] + red[256 + tid];
    __syncthreads();
    {   /* fold through W_A / W_phi (linearity of the member-mean); low waves -> hA, high -> hP */
        const int t2 = tid & 255;
        const int s = t2 >> 5, d2 = t2 & 31;
        const float* Wm = (tid < 256) ? WA : WP;
        float acc = 0.0f;
        #pragma unroll 8
        for (int dp = 0; dp < 32; dp++)
            acc = fmaf(Wm[d2*32 + dp], fe[s*32 + dp], acc);
        if (tid < 256) hA[t2] = acc; else hP[t2] = acc;
    }
    __syncthreads();

    /* per-thread clique constants: n = l + 64r */
    int   nn[4];
    float krow[4];
    const float m0 = (l == 0) ? 0.0f : 1.0f;
    float c18;
    { const float t1 = 1.0f + QF, t2 = t1*t1, t4 = t2*t2; c18 = t4*t4; }
    #pragma unroll
    for (int r = 0; r < 4; r++){
        nn[r] = l + 64*r;
        krow[r] = c18 - __expf(-0.125f * (float)__popc(nn[r]));
    }

    /* drive terms in REGS (loop-invariant): CAp, Dsp=ca*sin(Pin), Dcp=ca*cos(Pin).
       state {A,phi} -> LDS own-slot. scl_c = carried norm-clip scale. */
    float CAp[4][4], Dsp[4][4], Dcp[4][4];
    float scl_c[4] = {1.0f, 1.0f, 1.0f, 1.0f};
    float nrm0[4] = {0.f, 0.f, 0.f, 0.f};

    #pragma unroll
    for (int dd = 0; dd < 4; dd++){
        const int d = w*4 + dd;
        const float bAd = bA[d], bPd = bP[d];
        float gA_[8], gP_[8];
        #pragma unroll
        for (int s = 0; s < 8; s++){ gA_[s] = hA[s*32 + d]; gP_[s] = hP[s*32 + d]; }
        #pragma unroll
        for (int r = 0; r < 4; r++){
            const int pop = __popc(nn[r]);
            const float rdep = 1.0f / (float)(pop ? pop : 1);
            float sA = 0.0f, sP = 0.0f;
            #pragma unroll
            for (int s = 0; s < 8; s++){
                if ((nn[r] >> s) & 1){ sA += gA_[s]; sP += gP_[s]; }
            }
            const float uA  = fmaf(sA, rdep, bAd);
            const float uP  = fmaf(sP, rdep, bPd);
            const float Ain = softplus_f(uA);
            const float pin = PI_F * tanh_fast(uP);
            const float ca = dtiw * Ain;
            CAp[dd][r] = ca;
            Dsp[dd][r] = ca * __sinf(pin);
            Dcp[dd][r] = ca * __cosf(pin);
            if (USET){
                /* iter-0 peel: A1 = softplus(X + ca); phi1 = F0 + P0/A1 + ca*sin(pin-F0) */
                const int idx = d*256 + nn[r];
                const float An = softplus_f(Xc[idx] + ca);
                const float rr = __builtin_amdgcn_rcpf(An + 1e-8f);
                const float F0 = F0c[idx];
                float pb = fmaf(ca, __sinf(pin - F0), F0);
                ST[dd*4 + r][tid] = make_float2(An, fmaf(P0c[idx], rr, pb));
                nrm0[r] = fmaf(An, An, nrm0[r]);
            } else {
                const int nm1 = (nn[r] > 0) ? (nn[r] - 1) : 0;
                ST[dd*4 + r][tid] = make_float2(softplus_f(psiA0[nm1*32 + d]),
                                                psiP0[nm1*32 + d]);
            }
        }
        __builtin_amdgcn_sched_barrier(0);
    }

    if (USET){
        /* norm-clip for peeled iteration 0 -> carried scale only */
        #pragma unroll
        for (int r = 0; r < 4; r++) red[w*256 + nn[r]] = nrm0[r];
        __syncthreads();
        #pragma unroll
        for (int r = 0; r < 4; r++){
            const int n = nn[r];
            const float t = red[n]        + red[256 + n]  + red[512 + n]  + red[768 + n]
                          + red[1024 + n] + red[1280 + n] + red[1536 + n] + red[1792 + n];
            scl_c[r] = (t > 1.0f) ? rsqrtf(t) : 1.0f;
        }
        __syncthreads();   /* protect red against next writer */
    }

    /* prefetch dd=0 state for the first full iteration */
    float2 stn[4];
    #pragma unroll
    for (int r = 0; r < 4; r++) stn[r] = ST[r][tid];

    /* ---- full iterations (3 when peeled, 4 otherwise) ---- */
    const int NFULL = USET ? 3 : 4;
    for (int it = 0; it < NFULL; it++){
        float nrm[4] = {0.f, 0.f, 0.f, 0.f};
        #pragma unroll
        for (int dd = 0; dd < 4; dd++){
            float Al[4], ph[4], sp[4], cp[4];
            #pragma unroll
            for (int r = 0; r < 4; r++){
                Al[r] = stn[r].x * scl_c[r];     /* apply carried clip scale */
                ph[r] = stn[r].y;
            }
            if (dd < 3){                          /* prefetch next dd (own slot) */
                #pragma unroll
                for (int r = 0; r < 4; r++) stn[r] = ST[(dd+1)*4 + r][tid];
            }
            float x[5][4];
            {
                sp[0] = __sinf(ph[0]); cp[0] = __cosf(ph[0]);
                const float xa = Al[0] * m0;
                x[0][0] = xa;
                x[1][0] = sp[0] * m0;
                x[2][0] = cp[0] * m0;
                x[3][0] = xa * cp[0];
                x[4][0] = xa * sp[0];
            }
            #pragma unroll
            for (int r = 1; r < 4; r++){
                sp[r] = __sinf(ph[r]); cp[r] = __cosf(ph[r]);
                const float xa = Al[r];
                x[0][r] = xa;
                x[1][r] = sp[r];
                x[2][r] = cp[r];
                x[3][r] = xa * cp[r];
                x[4][r] = xa * sp[r];
            }
            bflyN<5>(x);
            #pragma unroll
            for (int r = 0; r < 4; r++){
                const float Ao   = Al[r];
                const float lapp = fmaf(-krow[r], Ao, x[0][r]);
                const float Vp   = fmaf(cp[r], x[3][r], sp[r]*x[4][r]);
                float Aarg = fmaf(c0, Ao, CAp[dd][r]);
                Aarg = fmaf(dta,  lapp, Aarg);
                Aarg = fmaf(dtpw, Vp,   Aarg);
                const float An = softplus_f(Aarg);
                const float Pp = fmaf(-sp[r], x[2][r], cp[r]*x[1][r]);
                const float rr = __builtin_amdgcn_rcpf(An + 1e-8f);
                float pb = fmaf(Dsp[dd][r], cp[r], ph[r]);
                pb = fmaf(-Dcp[dd][r], sp[r], pb);
                ST[dd*4 + r][tid] = make_float2(An, fmaf(dta*Ao, Pp*rr, pb));
                nrm[r] = fmaf(An, An, nrm[r]);
            }
            __builtin_amdgcn_sched_barrier(0);
        }
        /* prefetch next round's dd=0 (written this iter at dd=0; own slot, same thread) */
        #pragma unroll
        for (int r = 0; r < 4; r++) stn[r] = ST[r][tid];
        #pragma unroll
        for (int r = 0; r < 4; r++) red[w*256 + nn[r]] = nrm[r];
        __syncthreads();
        #pragma unroll
        for (int r = 0; r < 4; r++){
            const int n = nn[r];
            const float t = red[n]        + red[256 + n]  + red[512 + n]  + red[768 + n]
                          + red[1024 + n] + red[1280 + n] + red[1536 + n] + red[1792 + n];
            scl_c[r] = (t > 1.0f) ? rsqrtf(t) : 1.0f;
        }
        __syncthreads();   /* protect red against next iteration's writer */
    }

    /* ---- final iteration (peeled): phi-update dead -> 3-array butterfly, A-only epilogue ---- */
    {
        float nrm[4] = {0.f, 0.f, 0.f, 0.f};
        #pragma unroll
        for (int dd = 0; dd < 4; dd++){
            float Al[4], ph[4], sp[4], cp[4];
            #pragma unroll
            for (int r = 0; r < 4; r++){
                Al[r] = stn[r].x * scl_c[r];
                ph[r] = stn[r].y;
            }
            if (dd < 3){
                #pragma unroll
                for (int r = 0; r < 4; r++) stn[r] = ST[(dd+1)*4 + r][tid];
            }
            float y[3][4];
            {
                sp[0] = __sinf(ph[0]); cp[0] = __cosf(ph[0]);
                const float xa = Al[0] * m0;
                y[0][0] = xa;
                y[1][0] = xa * cp[0];
                y[2][0] = xa * sp[0];
            }
            #pragma unroll
            for (int r = 1; r < 4; r++){
                sp[r] = __sinf(ph[r]); cp[r] = __cosf(ph[r]);
                const float xa = Al[r];
                y[0][r] = xa;
                y[1][r] = xa * cp[r];
                y[2][r] = xa * sp[r];
            }
            bflyN<3>(y);
            #pragma unroll
            for (int r = 0; r < 4; r++){
                const float Ao   = Al[r];
                const float lapp = fmaf(-krow[r], Ao, y[0][r]);
                const float Vp   = fmaf(cp[r], y[1][r], sp[r]*y[2][r]);
                float Aarg = fmaf(c0, Ao, CAp[dd][r]);
                Aarg = fmaf(dta,  lapp, Aarg);
                Aarg = fmaf(dtpw, Vp,   Aarg);
                const float An = softplus_f(Aarg);
                ST[dd*4 + r][tid] = make_float2(An, 0.0f);
                nrm[r] = fmaf(An, An, nrm[r]);
            }
            __builtin_amdgcn_sched_barrier(0);
        }
        #pragma unroll
        for (int r = 0; r < 4; r++) red[w*256 + nn[r]] = nrm[r];
        __syncthreads();
        #pragma unroll
        for (int r = 0; r < 4; r++){
            const int n = nn[r];
            const float t = red[n]        + red[256 + n]  + red[512 + n]  + red[768 + n]
                          + red[1024 + n] + red[1280 + n] + red[1536 + n] + red[1792 + n];
            scl_c[r] = (t > 1.0f) ? rsqrtf(t) : 1.0f;
        }
        __syncthreads();   /* red is about to be reused as ac[] */
    }

    /* ---- readout: preload final A (apply carried scale + n==0 kill), then DPP wave-sums ---- */
    float Ar[4][4];
    #pragma unroll
    for (int dd = 0; dd < 4; dd++){
        #pragma unroll
        for (int r = 0; r < 4; r++)
            Ar[dd][r] = ST[dd*4 + r][tid].x * scl_c[r];
        Ar[dd][0] *= m0;   /* kill n==0 slot */
    }

    for (int c = 0; c < 32; c++){
        float wv[4];
        #pragma unroll
        for (int r = 0; r < 4; r++){
            const int idx = c*255 + nn[r] - 1;
            wv[r] = Wcomp[idx < 0 ? 0 : idx];
        }
        const float bc = bcomp[c];
        #pragma unroll
        for (int dd = 0; dd < 4; dd++){
            float v = wv[0] * Ar[dd][0];
            v = fmaf(wv[1], Ar[dd][1], v);
            v = fmaf(wv[2], Ar[dd][2], v);
            v = fmaf(wv[3], Ar[dd][3], v);
            v = wave_sum63(v);
            if (l == 63)
                ac[(w*4 + dd)*32 + c] = fmaxf(v + bc, 0.0f);
        }
    }
    __syncthreads();

    /* ro[k] = sum_j Wread[k][j] * ac[j] + bread[k]; k = 0..63 split over 4 partials */
    {
        const int k = tid >> 2, part = tid & 3;
        const float4* Wr4 = (const float4*)Wread + k*256;
        const float4* ac4 = (const float4*)ac;
        float s = 0.0f;
        #pragma unroll 4
        for (int jj = 0; jj < 64; jj++){
            const int j4 = part + 4*jj;
            const float4 wv = Wr4[j4];
            const float4 av = ac4[j4];
            s = fmaf(wv.x, av.x, s); s = fmaf(wv.y, av.y, s);
            s = fmaf(wv.z, av.z, s); s = fmaf(wv.w, av.w, s);
        }
        rop[tid] = s;
    }
    __syncthreads();
    if (tid < 32){
        const float ra = rop[tid*4] + rop[tid*4+1] + rop[tid*4+2] + rop[tid*4+3] + bread[tid];
        const int   t2 = tid + 32;
        const float rp = rop[t2*4] + rop[t2*4+1] + rop[t2*4+2] + rop[t2*4+3] + bread[t2];
        const float amp = softplus_f(ra);
        const float ph  = PI_F * tanhf(rp * pcpl);
        const float cph = __cosf(ph);
        /* PLANAR output (verified R7): chunk0 = Re(psi), chunk1 = amplitude, chunk2 = phase */
        const int o = b*32 + tid;
        out[o]         = amp * cph;   /* Re(psi) */
        out[Bb*32 + o] = amp;         /* amplitude */
        out[Bb*64 + o] = ph;          /* phase */
    }
}

extern "C" void kernel_launch(void* const* d_in, const int* in_sizes, int n_in,
                              void* d_out, int out_size, void* d_ws, size_t ws_size,
                              hipStream_t stream) {
    const float* ns      = (const float*)d_in[0];   /* [B][512] */
    const float* Ws      = (const float*)d_in[1];   /* [256][512] */
    const float* bs      = (const float*)d_in[2];   /* [256] */
    const float* WA      = (const float*)d_in[3];   /* [32][32] */
    const float* bA      = (const float*)d_in[4];   /* [32] */
    const float* WP      = (const float*)d_in[5];   /* [32][32] */
    const float* bP      = (const float*)d_in[6];   /* [32] */
    const float* psiA0   = (const float*)d_in[7];   /* [255*32] */
    const float* psiP0   = (const float*)d_in[8];   /* [255*32] */
    const float* Wcomp   = (const float*)d_in[9];   /* [32*255] */
    const float* bcomp   = (const float*)d_in[10];  /* [32] */
    const float* Wread   = (const float*)d_in[11];  /* [64*1024] */
    const float* bread   = (const float*)d_in[12];  /* [64] */
    const float* p_alpha = (const float*)d_in[13];
    const float* p_msq   = (const float*)d_in[14];
    const float* p_pw    = (const float*)d_in[15];
    const float* p_iw    = (const float*)d_in[16];
    const float* p_evo   = (const float*)d_in[17];
    const float* p_pcpl  = (const float*)d_in[18];

    const int Bb = in_sizes[0] / 512;               /* 1024 */

    const size_t need = (size_t)(512*256 + 3*32*256) * sizeof(float);
    if (ws_size >= need){
        float* WsT = (float*)d_ws;                  /* [512][256] */
        float* Xc  = WsT + 512*256;                 /* [32][256] each */
        float* P0c = Xc  + 32*256;
        float* F0c = P0c + 32*256;
        prep_kernel<<<33, 256, 0, stream>>>(Ws, psiA0, psiP0,
                                            p_alpha, p_msq, p_pw, p_iw, p_evo,
                                            WsT, Xc, P0c, F0c);
        fused_kernel<true><<<Bb, 512, 0, stream>>>(ns, Ws, WsT, bs, WA, bA, WP, bP,
                                                   psiA0, psiP0, Xc, P0c, F0c,
                                                   Wcomp, bcomp, Wread, bread,
                                                   p_alpha, p_msq, p_pw, p_iw,
                                                   p_evo, p_pcpl, (float*)d_out, Bb);
    } else {
        fused_kernel<false><<<Bb, 512, 0, stream>>>(ns, Ws, nullptr, bs, WA, bA, WP, bP,
                                                    psiA0, psiP0,
                                                    nullptr, nullptr, nullptr,
                                                    Wcomp, bcomp, Wread, bread,
                                                    p_alpha, p_msq, p_pw, p_iw,
                                                    p_evo, p_pcpl, (float*)d_out, Bb);
    }
}

// Round 12
// 269.549 us; speedup vs baseline: 1.2572x; 1.0541x over previous
//
#include <hip/hip_runtime.h>
#include <math.h>

#define PI_F   3.14159265358979f
#define QF     0.88249690258459546f   /* exp(-1/8) */
#define INV255 (1.0f/255.0f)

__device__ __forceinline__ float softplus_f(float x){
    return fmaxf(x, 0.0f) + __logf(1.0f + __expf(-fabsf(x)));
}
__device__ __forceinline__ float tanh_fast(float x){
    const float e = __expf(2.0f*x);
    return fmaf(-2.0f, __builtin_amdgcn_rcpf(e + 1.0f), 1.0f);
}

/* ---- lane exchanges (all HW-verified equivalent R1==R2; row_ror:8 verified R11) ---- */
template<int CTRL>
__device__ __forceinline__ float dppmov(float x){
    return __int_as_float(__builtin_amdgcn_mov_dpp(__float_as_int(x), CTRL, 0xF, 0xF, false));
}
__device__ __forceinline__ float lxor1 (float x){ return dppmov<0xB1>(x);  }  /* quad_perm(1,0,3,2) */
__device__ __forceinline__ float lxor2 (float x){ return dppmov<0x4E>(x);  }  /* quad_perm(2,3,0,1) */
__device__ __forceinline__ float lxor8 (float x){ return dppmov<0x128>(x); }  /* row_ror:8 == i^8   */
__device__ __forceinline__ float lxor4 (float x){ return __int_as_float(__builtin_amdgcn_ds_swizzle(__float_as_int(x), 0x101F)); }
__device__ __forceinline__ float lxor16(float x){ return __int_as_float(__builtin_amdgcn_ds_swizzle(__float_as_int(x), 0x401F)); }
__device__ __forceinline__ float lxor32(float x){ return __shfl_xor(x, 32, 64); }

/* Weighted-Hadamard butterfly, bits 0..5 on lanes, 6..7 on regs. Stages commute. */
template<int NA>
__device__ __forceinline__ void bflyN(float (&x)[NA][4]){
    const float qv = QF;
    #pragma unroll
    for (int a = 0; a < NA; a++){
        #pragma unroll
        for (int r = 0; r < 4; r++) x[a][r] = fmaf(lxor1 (x[a][r]), qv, x[a][r]);
    }
    #pragma unroll
    for (int a = 0; a < NA; a++){
        #pragma unroll
        for (int r = 0; r < 4; r++) x[a][r] = fmaf(lxor2 (x[a][r]), qv, x[a][r]);
    }
    #pragma unroll
    for (int a = 0; a < NA; a++){
        #pragma unroll
        for (int r = 0; r < 4; r++) x[a][r] = fmaf(lxor8 (x[a][r]), qv, x[a][r]);
    }
    #pragma unroll
    for (int a = 0; a < NA; a++){
        #pragma unroll
        for (int r = 0; r < 4; r++) x[a][r] = fmaf(lxor4 (x[a][r]), qv, x[a][r]);
    }
    #pragma unroll
    for (int a = 0; a < NA; a++){
        #pragma unroll
        for (int r = 0; r < 4; r++) x[a][r] = fmaf(lxor16(x[a][r]), qv, x[a][r]);
    }
    #pragma unroll
    for (int a = 0; a < NA; a++){
        #pragma unroll
        for (int r = 0; r < 4; r++) x[a][r] = fmaf(lxor32(x[a][r]), qv, x[a][r]);
    }
    #pragma unroll
    for (int a = 0; a < NA; a++){
        float t0 = x[a][0], t2 = x[a][2];
        x[a][0] = fmaf(QF, x[a][1], x[a][0]);
        x[a][1] = fmaf(QF, t0,      x[a][1]);
        x[a][2] = fmaf(QF, x[a][3], x[a][2]);
        x[a][3] = fmaf(QF, t2,      x[a][3]);
        t0 = x[a][0]; float t1 = x[a][1];
        x[a][0] = fmaf(QF, x[a][2], x[a][0]);
        x[a][1] = fmaf(QF, x[a][3], x[a][1]);
        x[a][2] = fmaf(QF, t0,      x[a][2]);
        x[a][3] = fmaf(QF, t1,      x[a][3]);
    }
}

/* ---- prep: blocks 0..31 transpose Ws -> WsT[512][256];
       block 32: iteration-0 peel constants X,P0,phi0 [32][256] (batch-independent) ---- */
__global__ __launch_bounds__(256) void prep_kernel(
        const float* __restrict__ Ws,    const float* __restrict__ psiA0,
        const float* __restrict__ psiP0, const float* __restrict__ p_alpha,
        const float* __restrict__ p_msq, const float* __restrict__ p_pw,
        const float* __restrict__ p_iw,  const float* __restrict__ p_evo,
        float* __restrict__ WsT,  float* __restrict__ Xc,  float* __restrict__ P0c,
        float* __restrict__ F0c)
{
    if (blockIdx.x < 32){
        __shared__ float tile[64][65];
        const int rt = blockIdx.x & 3, ct = blockIdx.x >> 2;
        const int r0 = rt*64, c0t = ct*64;
        const int tx = threadIdx.x & 63, ty = threadIdx.x >> 6;
        #pragma unroll
        for (int k = 0; k < 16; k++){
            const int row = ty*16 + k;
            tile[row][tx] = Ws[(r0+row)*512 + c0t + tx];
        }
        __syncthreads();
        #pragma unroll
        for (int k = 0; k < 16; k++){
            const int row = ty*16 + k;
            WsT[(c0t+row)*256 + r0 + tx] = tile[tx][row];
        }
        return;
    }
    /* block 32: batch-independent iteration-0 dynamics */
    const int tid = threadIdx.x;
    const int w = tid >> 6, l = tid & 63;
    const float alpha = p_alpha[0], msq = p_msq[0], pw = p_pw[0], iw = p_iw[0];
    const float dt   = 1.0f / (1.0f + __expf(-p_evo[0]));
    const float dta  = dt * alpha * INV255;
    const float dtpw = dt * pw * INV255;
    const float c0   = 1.0f - dt * (msq + iw);
    const float m0 = (l == 0) ? 0.0f : 1.0f;
    int nn[4]; float krow[4];
    float c18;
    { const float t1 = 1.0f + QF, t2 = t1*t1, t4 = t2*t2; c18 = t4*t4; }
    #pragma unroll
    for (int r = 0; r < 4; r++){
        nn[r] = l + 64*r;
        krow[r] = c18 - __expf(-0.125f * (float)__popc(nn[r]));
    }
    #pragma unroll
    for (int dd = 0; dd < 8; dd++){
        const int d = w*8 + dd;
        float A0[4], ph0[4], sp[4], cp[4];
        float x[5][4];
        #pragma unroll
        for (int r = 0; r < 4; r++){
            const int n = nn[r];
            A0[r]  = (n > 0) ? softplus_f(psiA0[(n-1)*32 + d]) : 0.0f;
            ph0[r] = (n > 0) ? psiP0[(n-1)*32 + d] : 0.0f;
            sp[r] = __sinf(ph0[r]); cp[r] = __cosf(ph0[r]);
            const float mk = (r == 0) ? m0 : 1.0f;
            const float xa = A0[r] * mk;
            x[0][r] = xa;
            x[1][r] = sp[r] * mk;
            x[2][r] = cp[r] * mk;
            x[3][r] = xa * cp[r];
            x[4][r] = xa * sp[r];
        }
        bflyN<5>(x);
        #pragma unroll
        for (int r = 0; r < 4; r++){
            const float Ao   = A0[r];
            const float lapp = fmaf(-krow[r], Ao, x[0][r]);
            const float Vp   = fmaf(cp[r], x[3][r], sp[r]*x[4][r]);
            const float Pp   = fmaf(-sp[r], x[2][r], cp[r]*x[1][r]);
            float X = c0 * Ao;
            X = fmaf(dta,  lapp, X);
            X = fmaf(dtpw, Vp,   X);
            const int idx = d*256 + nn[r];
            Xc[idx]  = X;
            P0c[idx] = dta * Ao * Pp;
            F0c[idx] = ph0[r];
        }
    }
}

/* ---------------- fused kernel: one block = one batch element, 512 threads (8 waves).
   R10/R11 winner structure: loop-invariant drive {CAp,Dsp,Dcp} in REGS, mutated
   {A,phi} streams through own-slot LDS ST (software-managed spill, zero scratch).
   77KB LDS -> 2 blocks/CU (barrier overlap). VALU budget ~147us, busy 73%.
   R12: VALU-op REMOVAL in the readout. The 128 wave_sum63 calls (768 DPP adds/
   thread, 60% overhead on the Ac contraction) are replaced by an LDS-transpose
   dot: final scaled A rewritten as AL[d][n] (overlaying dead ST), Wcomp staged
   zero-padded as WL[32][260] (straddles old ST/red boundary -> ST+red unified
   into POOL), each thread computes 2 (d,c) dots with float4 fma. Mapping
   c=l&31, d=w+8*(l>>5): AL reads wave-broadcast (free), WL 4-way worst (DS pipe
   has headroom). Also cuts Wcomp global loads 128->17/thread.
   peel-0 + 3 full iters + peel-4; carried norm-clip scale scl_c. ------- */
template<bool USET>
__global__ __launch_bounds__(512, 4) void fused_kernel(
        const float* __restrict__ ns,     /* [B][512] */
        const float* __restrict__ Ws,     /* [256][512] */
        const float* __restrict__ WsT,    /* [512][256] or null */
        const float* __restrict__ bs,     /* [256] */
        const float* __restrict__ WA,     /* [32][32] */
        const float* __restrict__ bA,     /* [32] */
        const float* __restrict__ WP,     /* [32][32] */
        const float* __restrict__ bP,     /* [32] */
        const float* __restrict__ psiA0,  /* [255*32] */
        const float* __restrict__ psiP0,  /* [255*32] */
        const float* __restrict__ Xc,     /* [32][256] or null */
        const float* __restrict__ P0c,    /* [32][256] or null */
        const float* __restrict__ F0c,    /* [32][256] or null */
        const float* __restrict__ Wcomp,  /* [32*255] */
        const float* __restrict__ bcomp,  /* [32] */
        const float* __restrict__ Wread,  /* [64*1024] */
        const float* __restrict__ bread,  /* [64] */
        const float* __restrict__ p_alpha, const float* __restrict__ p_msq,
        const float* __restrict__ p_pw,    const float* __restrict__ p_iw,
        const float* __restrict__ p_evo,   const float* __restrict__ p_pcpl,
        float* __restrict__ out, int Bb)
{
    /* POOL = old ST(16K floats) + red(2K floats) unified; 73.7KB + 5KB aux = 78848B
       -> 2 blocks/CU (16 waves/CU), same as R10/R11. */
    __shared__ __align__(16) float POOL[18432];
    __shared__ __align__(16) float hA[256];
    __shared__ __align__(16) float hP[256];
    __shared__ __align__(16) float nsb[512];
    __shared__ __align__(16) float fe[256];

    float2 (*ST)[512] = (float2(*)[512])POOL;   /* ST[k][tid], k=dd*4+r — own-slot */
    float* red = POOL + 16384;                  /* [2048] GEMV/norm partials */
    float* AL  = POOL;                          /* readout: [32][256] scaled A   */
    float* WL  = POOL + 8192;                   /* readout: [32][260] padded Wcomp */
    float* ac  = POOL + 16512;                  /* readout: [1024] (after WL end) */
    float* rop = POOL + 17536;                  /* readout: [512] */

    const int b   = blockIdx.x;
    const int tid = threadIdx.x;
    const int w   = tid >> 6, l = tid & 63;

    const float alpha = p_alpha[0], msq = p_msq[0], pw = p_pw[0], iw = p_iw[0];
    const float pcpl  = p_pcpl[0];
    const float dt    = 1.0f / (1.0f + __expf(-p_evo[0]));
    const float dta  = dt * alpha * INV255;
    const float dtpw = dt * pw * INV255;
    const float c0   = 1.0f - dt * (msq + iw);
    const float dtiw = dt * iw;

    /* ---- front-end: fe[f] = ns[b]·Ws_row(f) + bs[f]; 512 threads, 2 partials per f ---- */
    nsb[tid] = ns[b*512 + tid];
    __syncthreads();
    {
        const int k = tid >> 1, part = tid & 1;
        float f = (part == 0) ? bs[k] : 0.0f;
        if (USET){
            const float4* nb4 = (const float4*)nsb + part*64;
            const float*  colb = WsT + (part*64)*1024 + k;
            #pragma unroll 8
            for (int j4 = 0; j4 < 64; j4++){
                const float4 nv = nb4[j4];
                const float* col = colb + j4*1024;
                f = fmaf(col[0],   nv.x, f);
                f = fmaf(col[256], nv.y, f);
                f = fmaf(col[512], nv.z, f);
                f = fmaf(col[768], nv.w, f);
            }
        } else {
            const float4* wr  = (const float4*)(Ws + k*512) + part*64;
            const float4* nb4 = (const float4*)nsb + part*64;
            #pragma unroll 8
            for (int i = 0; i < 64; i++){
                const float4 wv = wr[i], nv = nb4[i];
                f = fmaf(wv.x, nv.x, f); f = fmaf(wv.y, nv.y, f);
                f = fmaf(wv.z, nv.z, f); f = fmaf(wv.w, nv.w, f);
            }
        }
        red[part*256 + k] = f;
    }
    __syncthreads();
    if (tid < 256) fe[tid] = red[tid] + red[256 + tid];
    __syncthreads();
    {   /* fold through W_A / W_phi (linearity of the member-mean); low waves -> hA, high -> hP */
        const int t2 = tid & 255;
        const int s = t2 >> 5, d2 = t2 & 31;
        const float* Wm = (tid < 256) ? WA : WP;
        float acc = 0.0f;
        #pragma unroll 8
        for (int dp = 0; dp < 32; dp++)
            acc = fmaf(Wm[d2*32 + dp], fe[s*32 + dp], acc);
        if (tid < 256) hA[t2] = acc; else hP[t2] = acc;
    }
    __syncthreads();

    /* per-thread clique constants: n = l + 64r */
    int   nn[4];
    float krow[4];
    const float m0 = (l == 0) ? 0.0f : 1.0f;
    float c18;
    { const float t1 = 1.0f + QF, t2 = t1*t1, t4 = t2*t2; c18 = t4*t4; }
    #pragma unroll
    for (int r = 0; r < 4; r++){
        nn[r] = l + 64*r;
        krow[r] = c18 - __expf(-0.125f * (float)__popc(nn[r]));
    }

    /* drive terms in REGS (loop-invariant): CAp, Dsp=ca*sin(Pin), Dcp=ca*cos(Pin).
       state {A,phi} -> LDS own-slot. scl_c = carried norm-clip scale. */
    float CAp[4][4], Dsp[4][4], Dcp[4][4];
    float scl_c[4] = {1.0f, 1.0f, 1.0f, 1.0f};
    float nrm0[4] = {0.f, 0.f, 0.f, 0.f};

    #pragma unroll
    for (int dd = 0; dd < 4; dd++){
        const int d = w*4 + dd;
        const float bAd = bA[d], bPd = bP[d];
        float gA_[8], gP_[8];
        #pragma unroll
        for (int s = 0; s < 8; s++){ gA_[s] = hA[s*32 + d]; gP_[s] = hP[s*32 + d]; }
        #pragma unroll
        for (int r = 0; r < 4; r++){
            const int pop = __popc(nn[r]);
            const float rdep = 1.0f / (float)(pop ? pop : 1);
            float sA = 0.0f, sP = 0.0f;
            #pragma unroll
            for (int s = 0; s < 8; s++){
                if ((nn[r] >> s) & 1){ sA += gA_[s]; sP += gP_[s]; }
            }
            const float uA  = fmaf(sA, rdep, bAd);
            const float uP  = fmaf(sP, rdep, bPd);
            const float Ain = softplus_f(uA);
            const float pin = PI_F * tanh_fast(uP);
            const float ca = dtiw * Ain;
            CAp[dd][r] = ca;
            Dsp[dd][r] = ca * __sinf(pin);
            Dcp[dd][r] = ca * __cosf(pin);
            if (USET){
                /* iter-0 peel: A1 = softplus(X + ca); phi1 = F0 + P0/A1 + ca*sin(pin-F0) */
                const int idx = d*256 + nn[r];
                const float An = softplus_f(Xc[idx] + ca);
                const float rr = __builtin_amdgcn_rcpf(An + 1e-8f);
                const float F0 = F0c[idx];
                float pb = fmaf(ca, __sinf(pin - F0), F0);
                ST[dd*4 + r][tid] = make_float2(An, fmaf(P0c[idx], rr, pb));
                nrm0[r] = fmaf(An, An, nrm0[r]);
            } else {
                const int nm1 = (nn[r] > 0) ? (nn[r] - 1) : 0;
                ST[dd*4 + r][tid] = make_float2(softplus_f(psiA0[nm1*32 + d]),
                                                psiP0[nm1*32 + d]);
            }
        }
        __builtin_amdgcn_sched_barrier(0);
    }

    if (USET){
        /* norm-clip for peeled iteration 0 -> carried scale only */
        #pragma unroll
        for (int r = 0; r < 4; r++) red[w*256 + nn[r]] = nrm0[r];
        __syncthreads();
        #pragma unroll
        for (int r = 0; r < 4; r++){
            const int n = nn[r];
            const float t = red[n]        + red[256 + n]  + red[512 + n]  + red[768 + n]
                          + red[1024 + n] + red[1280 + n] + red[1536 + n] + red[1792 + n];
            scl_c[r] = (t > 1.0f) ? rsqrtf(t) : 1.0f;
        }
        __syncthreads();   /* protect red against next writer */
    }

    /* prefetch dd=0 state for the first full iteration */
    float2 stn[4];
    #pragma unroll
    for (int r = 0; r < 4; r++) stn[r] = ST[r][tid];

    /* ---- full iterations (3 when peeled, 4 otherwise) ---- */
    const int NFULL = USET ? 3 : 4;
    for (int it = 0; it < NFULL; it++){
        float nrm[4] = {0.f, 0.f, 0.f, 0.f};
        #pragma unroll
        for (int dd = 0; dd < 4; dd++){
            float Al[4], ph[4], sp[4], cp[4];
            #pragma unroll
            for (int r = 0; r < 4; r++){
                Al[r] = stn[r].x * scl_c[r];     /* apply carried clip scale */
                ph[r] = stn[r].y;
            }
            if (dd < 3){                          /* prefetch next dd (own slot) */
                #pragma unroll
                for (int r = 0; r < 4; r++) stn[r] = ST[(dd+1)*4 + r][tid];
            }
            float x[5][4];
            {
                sp[0] = __sinf(ph[0]); cp[0] = __cosf(ph[0]);
                const float xa = Al[0] * m0;
                x[0][0] = xa;
                x[1][0] = sp[0] * m0;
                x[2][0] = cp[0] * m0;
                x[3][0] = xa * cp[0];
                x[4][0] = xa * sp[0];
            }
            #pragma unroll
            for (int r = 1; r < 4; r++){
                sp[r] = __sinf(ph[r]); cp[r] = __cosf(ph[r]);
                const float xa = Al[r];
                x[0][r] = xa;
                x[1][r] = sp[r];
                x[2][r] = cp[r];
                x[3][r] = xa * cp[r];
                x[4][r] = xa * sp[r];
            }
            bflyN<5>(x);
            #pragma unroll
            for (int r = 0; r < 4; r++){
                const float Ao   = Al[r];
                const float lapp = fmaf(-krow[r], Ao, x[0][r]);
                const float Vp   = fmaf(cp[r], x[3][r], sp[r]*x[4][r]);
                float Aarg = fmaf(c0, Ao, CAp[dd][r]);
                Aarg = fmaf(dta,  lapp, Aarg);
                Aarg = fmaf(dtpw, Vp,   Aarg);
                const float An = softplus_f(Aarg);
                const float Pp = fmaf(-sp[r], x[2][r], cp[r]*x[1][r]);
                const float rr = __builtin_amdgcn_rcpf(An + 1e-8f);
                float pb = fmaf(Dsp[dd][r], cp[r], ph[r]);
                pb = fmaf(-Dcp[dd][r], sp[r], pb);
                ST[dd*4 + r][tid] = make_float2(An, fmaf(dta*Ao, Pp*rr, pb));
                nrm[r] = fmaf(An, An, nrm[r]);
            }
            __builtin_amdgcn_sched_barrier(0);
        }
        /* prefetch next round's dd=0 (written this iter at dd=0; own slot, same thread) */
        #pragma unroll
        for (int r = 0; r < 4; r++) stn[r] = ST[r][tid];
        #pragma unroll
        for (int r = 0; r < 4; r++) red[w*256 + nn[r]] = nrm[r];
        __syncthreads();
        #pragma unroll
        for (int r = 0; r < 4; r++){
            const int n = nn[r];
            const float t = red[n]        + red[256 + n]  + red[512 + n]  + red[768 + n]
                          + red[1024 + n] + red[1280 + n] + red[1536 + n] + red[1792 + n];
            scl_c[r] = (t > 1.0f) ? rsqrtf(t) : 1.0f;
        }
        __syncthreads();   /* protect red against next iteration's writer */
    }

    /* ---- final iteration (peeled): phi-update dead -> 3-array butterfly, A-only epilogue ---- */
    {
        float nrm[4] = {0.f, 0.f, 0.f, 0.f};
        #pragma unroll
        for (int dd = 0; dd < 4; dd++){
            float Al[4], ph[4], sp[4], cp[4];
            #pragma unroll
            for (int r = 0; r < 4; r++){
                Al[r] = stn[r].x * scl_c[r];
                ph[r] = stn[r].y;
            }
            if (dd < 3){
                #pragma unroll
                for (int r = 0; r < 4; r++) stn[r] = ST[(dd+1)*4 + r][tid];
            }
            float y[3][4];
            {
                sp[0] = __sinf(ph[0]); cp[0] = __cosf(ph[0]);
                const float xa = Al[0] * m0;
                y[0][0] = xa;
                y[1][0] = xa * cp[0];
                y[2][0] = xa * sp[0];
            }
            #pragma unroll
            for (int r = 1; r < 4; r++){
                sp[r] = __sinf(ph[r]); cp[r] = __cosf(ph[r]);
                const float xa = Al[r];
                y[0][r] = xa;
                y[1][r] = xa * cp[r];
                y[2][r] = xa * sp[r];
            }
            bflyN<3>(y);
            #pragma unroll
            for (int r = 0; r < 4; r++){
                const float Ao   = Al[r];
                const float lapp = fmaf(-krow[r], Ao, y[0][r]);
                const float Vp   = fmaf(cp[r], y[1][r], sp[r]*y[2][r]);
                float Aarg = fmaf(c0, Ao, CAp[dd][r]);
                Aarg = fmaf(dta,  lapp, Aarg);
                Aarg = fmaf(dtpw, Vp,   Aarg);
                const float An = softplus_f(Aarg);
                ST[dd*4 + r][tid] = make_float2(An, 0.0f);
                nrm[r] = fmaf(An, An, nrm[r]);
            }
            __builtin_amdgcn_sched_barrier(0);
        }
        #pragma unroll
        for (int r = 0; r < 4; r++) red[w*256 + nn[r]] = nrm[r];
        __syncthreads();
        #pragma unroll
        for (int r = 0; r < 4; r++){
            const int n = nn[r];
            const float t = red[n]        + red[256 + n]  + red[512 + n]  + red[768 + n]
                          + red[1024 + n] + red[1280 + n] + red[1536 + n] + red[1792 + n];
            scl_c[r] = (t > 1.0f) ? rsqrtf(t) : 1.0f;
        }
        __syncthreads();
    }

    /* ---- readout stage 1 (LDS-transpose dot, replaces 128 wave_sum63):
       preload scaled A (reads own ST slots), barrier, overwrite ST region with
       AL[d][n] + stage WL[c][260] (zero-padded Wcomp), barrier, float4 dots. ---- */
    float Ar[4][4];
    #pragma unroll
    for (int dd = 0; dd < 4; dd++){
        #pragma unroll
        for (int r = 0; r < 4; r++)
            Ar[dd][r] = ST[dd*4 + r][tid].x * scl_c[r];
        Ar[dd][0] *= m0;   /* kill n==0 slot */
    }
    __syncthreads();       /* all ST reads complete before AL overwrite */

    #pragma unroll
    for (int dd = 0; dd < 4; dd++)
        #pragma unroll
        for (int r = 0; r < 4; r++)
            AL[(w*4 + dd)*256 + nn[r]] = Ar[dd][r];
    for (int i = tid; i < 8320; i += 512){     /* WL[c][n]: n in [1,255] -> Wcomp, else 0 */
        const int c = i / 260, n = i - c*260;
        WL[i] = (n >= 1 && n <= 255) ? Wcomp[c*255 + n - 1] : 0.0f;
    }
    __syncthreads();

    {   /* thread covers (c = l&31, d1 = w + 8*(l>>5)) and (c, d1+16).
           AL reads: 32 lanes share d -> broadcast (free). WL reads: 4-way worst. */
        const int c  = l & 31;
        const int d1 = w + 8*(l >> 5);
        const float4* AL4 = (const float4*)AL;
        const float4* WL4 = (const float4*)WL;   /* row stride 65 float4 (260 f) */
        float s1 = 0.0f, s2 = 0.0f;
        #pragma unroll 8
        for (int j = 0; j < 64; j++){
            const float4 wv = WL4[c*65 + j];
            const float4 a1 = AL4[d1*64 + j];
            const float4 a2 = AL4[(d1+16)*64 + j];
            s1 = fmaf(wv.x, a1.x, s1); s1 = fmaf(wv.y, a1.y, s1);
            s1 = fmaf(wv.z, a1.z, s1); s1 = fmaf(wv.w, a1.w, s1);
            s2 = fmaf(wv.x, a2.x, s2); s2 = fmaf(wv.y, a2.y, s2);
            s2 = fmaf(wv.z, a2.z, s2); s2 = fmaf(wv.w, a2.w, s2);
        }
        const float bc = bcomp[c];
        ac[d1*32 + c]        = fmaxf(s1 + bc, 0.0f);
        ac[(d1 + 16)*32 + c] = fmaxf(s2 + bc, 0.0f);
    }
    __syncthreads();

    /* ro[k] = sum_j Wread[k][j] * ac[j] + bread[k]; k = 0..63 split over 4 partials */
    {
        const int k = tid >> 2, part = tid & 3;
        const float4* Wr4 = (const float4*)Wread + k*256;
        const float4* ac4 = (const float4*)ac;
        float s = 0.0f;
        #pragma unroll 4
        for (int jj = 0; jj < 64; jj++){
            const int j4 = part + 4*jj;
            const float4 wv = Wr4[j4];
            const float4 av = ac4[j4];
            s = fmaf(wv.x, av.x, s); s = fmaf(wv.y, av.y, s);
            s = fmaf(wv.z, av.z, s); s = fmaf(wv.w, av.w, s);
        }
        rop[tid] = s;
    }
    __syncthreads();
    if (tid < 32){
        const float ra = rop[tid*4] + rop[tid*4+1] + rop[tid*4+2] + rop[tid*4+3] + bread[tid];
        const int   t2 = tid + 32;
        const float rp = rop[t2*4] + rop[t2*4+1] + rop[t2*4+2] + rop[t2*4+3] + bread[t2];
        const float amp = softplus_f(ra);
        const float ph  = PI_F * tanhf(rp * pcpl);
        const float cph = __cosf(ph);
        /* PLANAR output (verified R7): chunk0 = Re(psi), chunk1 = amplitude, chunk2 = phase */
        const int o = b*32 + tid;
        out[o]         = amp * cph;   /* Re(psi) */
        out[Bb*32 + o] = amp;         /* amplitude */
        out[Bb*64 + o] = ph;          /* phase */
    }
}

extern "C" void kernel_launch(void* const* d_in, const int* in_sizes, int n_in,
                              void* d_out, int out_size, void* d_ws, size_t ws_size,
                              hipStream_t stream) {
    const float* ns      = (const float*)d_in[0];   /* [B][512] */
    const float* Ws      = (const float*)d_in[1];   /* [256][512] */
    const float* bs      = (const float*)d_in[2];   /* [256] */
    const float* WA      = (const float*)d_in[3];   /* [32][32] */
    const float* bA      = (const float*)d_in[4];   /* [32] */
    const float* WP      = (const float*)d_in[5];   /* [32][32] */
    const float* bP      = (const float*)d_in[6];   /* [32] */
    const float* psiA0   = (const float*)d_in[7];   /* [255*32] */
    const float* psiP0   = (const float*)d_in[8];   /* [255*32] */
    const float* Wcomp   = (const float*)d_in[9];   /* [32*255] */
    const float* bcomp   = (const float*)d_in[10];  /* [32] */
    const float* Wread   = (const float*)d_in[11];  /* [64*1024] */
    const float* bread   = (const float*)d_in[12];  /* [64] */
    const float* p_alpha = (const float*)d_in[13];
    const float* p_msq   = (const float*)d_in[14];
    const float* p_pw    = (const float*)d_in[15];
    const float* p_iw    = (const float*)d_in[16];
    const float* p_evo   = (const float*)d_in[17];
    const float* p_pcpl  = (const float*)d_in[18];

    const int Bb = in_sizes[0] / 512;               /* 1024 */

    const size_t need = (size_t)(512*256 + 3*32*256) * sizeof(float);
    if (ws_size >= need){
        float* WsT = (float*)d_ws;                  /* [512][256] */
        float* Xc  = WsT + 512*256;                 /* [32][256] each */
        float* P0c = Xc  + 32*256;
        float* F0c = P0c + 32*256;
        prep_kernel<<<33, 256, 0, stream>>>(Ws, psiA0, psiP0,
                                            p_alpha, p_msq, p_pw, p_iw, p_evo,
                                            WsT, Xc, P0c, F0c);
        fused_kernel<true><<<Bb, 512, 0, stream>>>(ns, Ws, WsT, bs, WA, bA, WP, bP,
                                                   psiA0, psiP0, Xc, P0c, F0c,
                                                   Wcomp, bcomp, Wread, bread,
                                                   p_alpha, p_msq, p_pw, p_iw,
                                                   p_evo, p_pcpl, (float*)d_out, Bb);
    } else {
        fused_kernel<false><<<Bb, 512, 0, stream>>>(ns, Ws, nullptr, bs, WA, bA, WP, bP,
                                                    psiA0, psiP0,
                                                    nullptr, nullptr, nullptr,
                                                    Wcomp, bcomp, Wread, bread,
                                                    p_alpha, p_msq, p_pw, p_iw,
                                                    p_evo, p_pcpl, (float*)d_out, Bb);
    }
}